// Round 2
// baseline (1151.402 us; speedup 1.0000x reference)
//
#include <hip/hip_runtime.h>

// SatelliteImageGNN: 3-layer GCN on a 768x768 8-neighbor grid + pixel shuffle.
// GCN layer = dinv * boxsum3x3(dinv .* h) @ W + b ; dinv from position.
// Round-2 structure: planar channel-group LDS (conflict-free b128), 16-ch
// K-split of layer 2 (acc in VGPRs), layer-3 matvec BEFORE boxsum.
// LDS 68.2 KB -> 2 blocks/CU.

constexpr int HH   = 768;
constexpr int SS   = 3;
constexpr int TILE = 16;
constexpr int NB   = HH / TILE;   // 48
constexpr int R1   = TILE + 6;    // 22
constexpr int R2   = TILE + 4;    // 20
constexpr int R3   = TILE + 2;    // 18
constexpr int NT   = 512;
constexpr int N1   = R1 * R1;     // 484
constexpr int N2   = R2 * R2;     // 400
constexpr int N3   = R3 * R3;     // 324
constexpr int NO   = TILE * TILE; // 256

// ---- LDS layout (float offsets; all 16B aligned) ----
constexpr int G0OFF = 0;                  // [484][4]            = 1936
constexpr int S0OFF = G0OFF + N1 * 4;     // 1936: [400][4]      = 1600 (ends 3536)
constexpr int TOFF  = 0;                  // t: 3 planes x [324][4] = 3888 (overlays g0/s0, both dead)
constexpr int XOFF  = 3888;
constexpr int G1OFF = XOFF;               // 4 planes x [400][4] = 6400
constexpr int S1OFF = XOFF + 6400;        // 4 planes x [324][4] = 5184 (ends 15472)
constexpr int G2OFF = XOFF;               // 8 planes x [324][4] = 10368 (overlays g1+s1)
constexpr int OUTOFF= XOFF;               // [256][12] = 3072 (overlays g2 after mm3')
constexpr int WOFF  = XOFF + 11584;       // 15472
constexpr int W1OFF = WOFF;               // [3][32]  = 96
constexpr int W2OFF = WOFF + 96;          // [32][32] = 1024
constexpr int W3OFF = WOFF + 1120;        // [32][12] = 384 (9 cols + zero pad)
constexpr int B1OFF = WOFF + 1504;        // 32
constexpr int B2OFF = WOFF + 1536;        // 32
constexpr int B3OFF = WOFF + 1568;        // 12 (9 + zero pad)
constexpr int SMEMF = WOFF + 1580;        // 17052 floats = 68208 B

__device__ __forceinline__ float dinv_of(int gi, int gj) {
    int e = (1 + (gi > 0) + (gi < HH - 1)) * (1 + (gj > 0) + (gj < HH - 1));
    return e == 9 ? 0.33333334f : (e == 6 ? 0.40824829f : 0.5f);
}

__device__ __forceinline__ void fma4(float4& acc, float a, const float4 w) {
    acc.x += a * w.x; acc.y += a * w.y; acc.z += a * w.z; acc.w += a * w.w;
}
__device__ __forceinline__ void add4(float4& acc, const float4 v) {
    acc.x += v.x; acc.y += v.y; acc.z += v.z; acc.w += v.w;
}

__global__ __launch_bounds__(NT, 4) void gnn_fused(
    const float* __restrict__ x,
    const float* __restrict__ W1, const float* __restrict__ b1,
    const float* __restrict__ W2, const float* __restrict__ b2,
    const float* __restrict__ W3, const float* __restrict__ b3,
    float* __restrict__ out)
{
    __shared__ __align__(16) float smem[SMEMF];
    const int tid = threadIdx.x;
    const int bi = blockIdx.x / NB;
    const int bj = blockIdx.x % NB;
    const int oi = bi * TILE, oj = bj * TILE;

    // ---- stage weights (padded/zeroed) + g0 = dinv .* x on R1 ----
    for (int i = tid; i < 96;   i += NT) smem[W1OFF + i] = W1[i];
    for (int i = tid; i < 1024; i += NT) smem[W2OFF + i] = W2[i];
    for (int i = tid; i < 384;  i += NT) {
        int r = i / 12, c = i % 12;
        smem[W3OFF + i] = (c < 9) ? W3[r * 9 + c] : 0.f;
    }
    if (tid < 32) { smem[B1OFF + tid] = b1[tid]; smem[B2OFF + tid] = b2[tid]; }
    if (tid < 12) { smem[B3OFF + tid] = (tid < 9) ? b3[tid] : 0.f; }

    for (int n = tid; n < N1; n += NT) {
        int li = n / R1, lj = n % R1;
        int gi = oi - 3 + li, gj = oj - 3 + lj;
        float4 v = {0.f, 0.f, 0.f, 0.f};
        if ((unsigned)gi < HH && (unsigned)gj < HH) {
            float d = dinv_of(gi, gj);
            const float* xp = x + 3 * ((size_t)gi * HH + gj);
            v.x = d * xp[0]; v.y = d * xp[1]; v.z = d * xp[2];
        }
        *(float4*)&smem[G0OFF + n * 4] = v;
    }
    __syncthreads();

    // ---- bs1: s0 = boxsum(g0) on R2 ----
    for (int n = tid; n < N2; n += NT) {
        int li = n / R2, lj = n % R2;
        float4 s = {0.f, 0.f, 0.f, 0.f};
        #pragma unroll
        for (int di = 0; di < 3; ++di)
            #pragma unroll
            for (int dj = 0; dj < 3; ++dj)
                add4(s, *(const float4*)&smem[G0OFF + ((li + di) * R1 + (lj + dj)) * 4]);
        *(float4*)&smem[S0OFF + n * 4] = s;
    }
    __syncthreads();

    float4 acc[6];
    #pragma unroll
    for (int i = 0; i < 6; ++i) acc[i] = make_float4(0.f, 0.f, 0.f, 0.f);

    // ---- middle section, K-split into two 16-channel halves ----
    for (int h = 0; h < 2; ++h) {
        const int cbase = 16 * h;
        // mm1: g1h = dinv*relu(dinv*(s0@W1[:,16h:16h+16])+b1) on R2, planar
        for (int item = tid; item < 4 * N2; item += NT) {
            int c4 = item / N2, n = item - c4 * N2;
            int li = n / R2, lj = n % R2;
            int gi = oi - 2 + li, gj = oj - 2 + lj;
            float4 g = {0.f, 0.f, 0.f, 0.f};
            if ((unsigned)gi < HH && (unsigned)gj < HH) {
                float d = dinv_of(gi, gj);
                int cb = cbase + 4 * c4;
                float4 s = *(const float4*)&smem[S0OFF + n * 4];
                float4 a = {0.f, 0.f, 0.f, 0.f};
                fma4(a, s.x, *(const float4*)&smem[W1OFF + 0 * 32 + cb]);
                fma4(a, s.y, *(const float4*)&smem[W1OFF + 1 * 32 + cb]);
                fma4(a, s.z, *(const float4*)&smem[W1OFF + 2 * 32 + cb]);
                float4 bb = *(const float4*)&smem[B1OFF + cb];
                g.x = d * fmaxf(d * a.x + bb.x, 0.f);
                g.y = d * fmaxf(d * a.y + bb.y, 0.f);
                g.z = d * fmaxf(d * a.z + bb.z, 0.f);
                g.w = d * fmaxf(d * a.w + bb.w, 0.f);
            }
            *(float4*)&smem[G1OFF + item * 4] = g;   // plane c4, node n
        }
        __syncthreads();

        // bs2: s1h = boxsum(g1h) on R3, planar
        for (int item = tid; item < 4 * N3; item += NT) {
            int p = item / N3, n = item - p * N3;
            int li = n / R3, lj = n % R3;
            float4 s = {0.f, 0.f, 0.f, 0.f};
            #pragma unroll
            for (int di = 0; di < 3; ++di)
                #pragma unroll
                for (int dj = 0; dj < 3; ++dj)
                    add4(s, *(const float4*)&smem[G1OFF + (p * N2 + (li + di) * R2 + (lj + dj)) * 4]);
            *(float4*)&smem[S1OFF + item * 4] = s;
        }
        __syncthreads();

        // mm2: acc += s1h @ W2[16h:16h+16, :]   (registers, both halves)
        #pragma unroll
        for (int it = 0; it < 6; ++it) {
            int item = it * NT + tid;
            if (item < 8 * N3) {
                int c4 = item / N3, n = item - c4 * N3;
                float4 a = acc[it];
                #pragma unroll
                for (int k4 = 0; k4 < 4; ++k4) {
                    float4 v = *(const float4*)&smem[S1OFF + (k4 * N3 + n) * 4];
                    fma4(a, v.x, *(const float4*)&smem[W2OFF + (cbase + 4 * k4 + 0) * 32 + 4 * c4]);
                    fma4(a, v.y, *(const float4*)&smem[W2OFF + (cbase + 4 * k4 + 1) * 32 + 4 * c4]);
                    fma4(a, v.z, *(const float4*)&smem[W2OFF + (cbase + 4 * k4 + 2) * 32 + 4 * c4]);
                    fma4(a, v.w, *(const float4*)&smem[W2OFF + (cbase + 4 * k4 + 3) * 32 + 4 * c4]);
                }
                acc[it] = a;
            }
        }
        __syncthreads();   // protects s1 (h=0->h=1) and g1/s1 region before g2 write
    }

    // ---- g2 = dinv*relu(dinv*acc+b2) on R3, planar (overlays g1+s1) ----
    #pragma unroll
    for (int it = 0; it < 6; ++it) {
        int item = it * NT + tid;
        if (item < 8 * N3) {
            int c4 = item / N3, n = item - c4 * N3;
            int li = n / R3, lj = n % R3;
            int gi = oi - 1 + li, gj = oj - 1 + lj;
            float4 g = {0.f, 0.f, 0.f, 0.f};
            if ((unsigned)gi < HH && (unsigned)gj < HH) {
                float d = dinv_of(gi, gj);
                float4 bb = *(const float4*)&smem[B2OFF + 4 * c4];
                float4 a = acc[it];
                g.x = d * fmaxf(d * a.x + bb.x, 0.f);
                g.y = d * fmaxf(d * a.y + bb.y, 0.f);
                g.z = d * fmaxf(d * a.z + bb.z, 0.f);
                g.w = d * fmaxf(d * a.w + bb.w, 0.f);
            }
            *(float4*)&smem[G2OFF + item * 4] = g;
        }
    }
    __syncthreads();

    // ---- mm3': t = g2 @ W3 on R3 (matvec BEFORE boxsum; they commute) ----
    for (int item = tid; item < 3 * N3; item += NT) {
        int p = item / N3, n = item - p * N3;
        float4 a = {0.f, 0.f, 0.f, 0.f};
        #pragma unroll
        for (int k4 = 0; k4 < 8; ++k4) {
            float4 v = *(const float4*)&smem[G2OFF + (k4 * N3 + n) * 4];
            fma4(a, v.x, *(const float4*)&smem[W3OFF + (4 * k4 + 0) * 12 + 4 * p]);
            fma4(a, v.y, *(const float4*)&smem[W3OFF + (4 * k4 + 1) * 12 + 4 * p]);
            fma4(a, v.z, *(const float4*)&smem[W3OFF + (4 * k4 + 2) * 12 + 4 * p]);
            fma4(a, v.w, *(const float4*)&smem[W3OFF + (4 * k4 + 3) * 12 + 4 * p]);
        }
        *(float4*)&smem[TOFF + item * 4] = a;   // t plane p, node n (overlays g0/s0)
    }
    __syncthreads();

    // ---- bs3' + epilogue: out9 = dinv*boxsum(t) + b3 -> outbuf [256][12] ----
    for (int item = tid; item < 3 * NO; item += NT) {
        int p = item / NO, n = item - p * NO;
        int li = n / TILE, lj = n % TILE;
        float4 s = {0.f, 0.f, 0.f, 0.f};
        #pragma unroll
        for (int di = 0; di < 3; ++di)
            #pragma unroll
            for (int dj = 0; dj < 3; ++dj)
                add4(s, *(const float4*)&smem[TOFF + (p * N3 + (li + di) * R3 + (lj + dj)) * 4]);
        float d = dinv_of(oi + li, oj + lj);
        float4 bb = *(const float4*)&smem[B3OFF + 4 * p];
        float4 o;
        o.x = d * s.x + bb.x; o.y = d * s.y + bb.y;
        o.z = d * s.z + bb.z; o.w = d * s.w + bb.w;
        *(float4*)&smem[OUTOFF + n * 12 + 4 * p] = o;   // overlays g2 (dead)
    }
    __syncthreads();

    // ---- pixel-shuffle write, float4 global stores ----
    // out pixel (oi*3+rr, oj*3+cc): rr=ii*3+si, cc=jj*3+sj -> outbuf[(ii*16+jj)*12 + si*3+sj]
    for (int q = tid; q < NO * 9 / 4; q += NT) {    // 576 float4 stores
        int rr = q / 12, cc0 = 4 * (q % 12);
        int ii = rr / 3, si = rr % 3;
        float4 o;
        {
            int cc = cc0 + 0, jj = cc / 3, sj = cc % 3;
            o.x = smem[OUTOFF + (ii * TILE + jj) * 12 + si * 3 + sj];
        }
        {
            int cc = cc0 + 1, jj = cc / 3, sj = cc % 3;
            o.y = smem[OUTOFF + (ii * TILE + jj) * 12 + si * 3 + sj];
        }
        {
            int cc = cc0 + 2, jj = cc / 3, sj = cc % 3;
            o.z = smem[OUTOFF + (ii * TILE + jj) * 12 + si * 3 + sj];
        }
        {
            int cc = cc0 + 3, jj = cc / 3, sj = cc % 3;
            o.w = smem[OUTOFF + (ii * TILE + jj) * 12 + si * 3 + sj];
        }
        *(float4*)&out[(size_t)(oi * SS + rr) * (HH * SS) + oj * SS + cc0] = o;
    }
}

extern "C" void kernel_launch(void* const* d_in, const int* in_sizes, int n_in,
                              void* d_out, int out_size, void* d_ws, size_t ws_size,
                              hipStream_t stream) {
    const float* x  = (const float*)d_in[0];
    // d_in[1] = edge_index (int32) — fixed grid; derived analytically.
    const float* W1 = (const float*)d_in[2];
    const float* b1 = (const float*)d_in[3];
    const float* W2 = (const float*)d_in[4];
    const float* b2 = (const float*)d_in[5];
    const float* W3 = (const float*)d_in[6];
    const float* b3 = (const float*)d_in[7];
    float* out = (float*)d_out;

    dim3 grid(NB * NB), block(NT);
    gnn_fused<<<grid, block, 0, stream>>>(x, W1, b1, W2, b2, W3, b3, out);
}

// Round 3
// 100.811 us; speedup vs baseline: 11.4214x; 11.4214x over previous
//
#include <hip/hip_runtime.h>

// SatelliteImageGNN: 3-layer GCN on a 768x768 8-neighbor grid + pixel shuffle.
// layer = dinv * boxsum3x3(dinv .* h) @ W + b ; dinv from position (edge_index unused).
// Round-3: streaming phases only (NO cross-barrier register state -> no scratch),
// planar float4 LDS (conflict-free), dinv masks precomputed (boundary via dinv=0),
// 4-way K-split of layer 1, fused mm2+mm3 per node (no g2 buffer),
// LDS 80,080 B -> 2 blocks/CU.

constexpr int HH   = 768;
constexpr int SS   = 3;
constexpr int TILE = 16;
constexpr int NB   = HH / TILE;   // 48
constexpr int NT   = 512;

constexpr int R1 = 22, R2 = 20, R3 = 18;
constexpr int N1  = R1 * R1;      // 484 (stride 22, 22 rows)
constexpr int S0N = R2 * R1;      // 440 (20 rows x stride 22; cols 20,21 junk)
constexpr int S1N = R3 * R3;      // 324 (stride 18, exact)
constexpr int ON  = TILE * TILE;  // 256

// ---- LDS float offsets ----
constexpr int G0O  = 0;                  // 486 float4 (484 + 2 pad) = 1944
constexpr int S0O  = G0O + 486 * 4;      // 1944 : 440 float4 = 1760
constexpr int G1QO = S0O + 440 * 4;      // 3704 : 2 planes x 440 float4 = 3520
constexpr int S1O  = G1QO + 880 * 4;     // 7224 : 8 planes x 324 float4 = 10368
constexpr int D2O  = S1O + 2592 * 4;     // 17592 : 440
constexpr int D3O  = D2O + 440;          // 18032 : 324
constexpr int DOO  = D3O + 324;          // 18356 : 256
constexpr int W2L  = DOO + 256;          // 18612 : 1024 ([32][32])
constexpr int W3L  = W2L + 1024;         // 19636 : 384  ([32][12], cols 9..11 zero)
constexpr int SMEMF= W3L + 384;          // 20020 floats = 80,080 B

constexpr int TBO  = 0;                  // t: 3 planes x 324 float4 = 3888 (overlays G0..G1Q = 7224)
constexpr int OUTB = S1O;                // outbuf [256][12] = 3072 (overlays S1)

__device__ __forceinline__ float dinv_of(int gi, int gj) {
    int e = (1 + (gi > 0) + (gi < HH - 1)) * (1 + (gj > 0) + (gj < HH - 1));
    return e == 9 ? 0.33333334f : (e == 6 ? 0.40824829f : 0.5f);
}
__device__ __forceinline__ void add4(float4& a, const float4 v) {
    a.x += v.x; a.y += v.y; a.z += v.z; a.w += v.w;
}

#define FMA4(acc, s, ptr) { const float4 _w = *(const float4*)(ptr); \
    acc.x += (s) * _w.x; acc.y += (s) * _w.y; acc.z += (s) * _w.z; acc.w += (s) * _w.w; }

__global__ __launch_bounds__(NT) void gnn_fused(
    const float* __restrict__ x,
    const float* __restrict__ W1, const float* __restrict__ b1,
    const float* __restrict__ W2, const float* __restrict__ b2,
    const float* __restrict__ W3, const float* __restrict__ b3,
    float* __restrict__ out)
{
    __shared__ __align__(16) float smem[SMEMF];
    const int tid = threadIdx.x;
    const int bi = blockIdx.x / NB;
    const int bj = blockIdx.x % NB;
    const int oi = bi * TILE, oj = bj * TILE;

    // ================= phase 0: weights + g0 + dinv planes =================
    for (int i = tid; i < 1024; i += NT) smem[W2L + i] = W2[i];
    for (int i = tid; i < 384;  i += NT) {
        int r = i / 12, c = i - r * 12;
        smem[W3L + i] = (c < 9) ? W3[r * 9 + c] : 0.f;
    }
    for (int n = tid; n < N1; n += NT) {          // g0 = dinv .* x  (22x22)
        int li = n / R1, lj = n - li * R1;
        int gi = oi - 3 + li, gj = oj - 3 + lj;
        float4 v = {0.f, 0.f, 0.f, 0.f};
        if ((unsigned)gi < HH && (unsigned)gj < HH) {
            float d = dinv_of(gi, gj);
            const float* xp = x + 3 * ((size_t)gi * HH + gj);
            v.x = d * xp[0]; v.y = d * xp[1]; v.z = d * xp[2];
        }
        *(float4*)&smem[G0O + n * 4] = v;
    }
    if (tid < 2) *(float4*)&smem[G0O + (N1 + tid) * 4] = make_float4(0.f, 0.f, 0.f, 0.f);
    for (int n = tid; n < S0N; n += NT) {         // dinv on R2 domain (0 = junk/out-of-grid)
        int li = n / R1, lj = n - li * R1;
        int gi = oi - 2 + li, gj = oj - 2 + lj;
        float v = 0.f;
        if (lj < R2 && (unsigned)gi < HH && (unsigned)gj < HH) v = dinv_of(gi, gj);
        smem[D2O + n] = v;
    }
    for (int n = tid; n < S1N; n += NT) {         // dinv on R3 domain
        int li = n / R3, lj = n - li * R3;
        int gi = oi - 1 + li, gj = oj - 1 + lj;
        float v = 0.f;
        if ((unsigned)gi < HH && (unsigned)gj < HH) v = dinv_of(gi, gj);
        smem[D3O + n] = v;
    }
    for (int n = tid; n < ON; n += NT) {          // dinv on output tile
        int li = n >> 4, lj = n & 15;
        smem[DOO + n] = dinv_of(oi + li, oj + lj);
    }
    __syncthreads();

    // ================= bs1: s0 = boxsum(g0), 3 ch =================
    for (int n = tid; n < S0N; n += NT) {
        float4 s = {0.f, 0.f, 0.f, 0.f};
        #pragma unroll
        for (int di = 0; di < 3; ++di)
            #pragma unroll
            for (int dj = 0; dj < 3; ++dj)
                add4(s, *(const float4*)&smem[G0O + (n + di * R1 + dj) * 4]);
        *(float4*)&smem[S0O + n * 4] = s;
    }
    __syncthreads();

    // ====== layer-1 + bs2, 4-way K-split (8 ch per pass, no reg carry) ======
    #pragma unroll
    for (int h = 0; h < 4; ++h) {
        // mm1: g1 quads q=2h+p on R2 domain
        #pragma unroll
        for (int p = 0; p < 2; ++p) {
            const int q = 2 * h + p;
            for (int n = tid; n < S0N; n += NT) {
                float d = smem[D2O + n];
                float4 s = *(const float4*)&smem[S0O + n * 4];
                float4 a = {0.f, 0.f, 0.f, 0.f};
                FMA4(a, s.x, &W1[0 * 32 + 4 * q]);
                FMA4(a, s.y, &W1[1 * 32 + 4 * q]);
                FMA4(a, s.z, &W1[2 * 32 + 4 * q]);
                const float4 bb = *(const float4*)&b1[4 * q];
                float4 g;
                g.x = d * fmaxf(d * a.x + bb.x, 0.f);
                g.y = d * fmaxf(d * a.y + bb.y, 0.f);
                g.z = d * fmaxf(d * a.z + bb.z, 0.f);
                g.w = d * fmaxf(d * a.w + bb.w, 0.f);
                *(float4*)&smem[G1QO + (p * S0N + n) * 4] = g;
            }
        }
        __syncthreads();
        // bs2: s1 planes q=2h+p on R3 domain (stride 18)
        #pragma unroll
        for (int p = 0; p < 2; ++p) {
            const int q = 2 * h + p;
            for (int n = tid; n < S1N; n += NT) {
                int li = n / R3, lj = n - li * R3;
                int src = li * R1 + lj;
                float4 s = {0.f, 0.f, 0.f, 0.f};
                #pragma unroll
                for (int di = 0; di < 3; ++di)
                    #pragma unroll
                    for (int dj = 0; dj < 3; ++dj)
                        add4(s, *(const float4*)&smem[G1QO + (p * S0N + src + di * R1 + dj) * 4]);
                *(float4*)&smem[S1O + (q * S1N + n) * 4] = s;
            }
        }
        __syncthreads();
    }

    // ====== fused mm2+mm3 per node: t = g2 @ W3, g2 in named regs only ======
    if (tid < S1N) {
        const int n = tid;
        const float d = smem[D3O + n];
        float4 a0 = {0,0,0,0}, a1 = {0,0,0,0}, a2 = {0,0,0,0}, a3 = {0,0,0,0};
        float4 a4 = {0,0,0,0}, a5 = {0,0,0,0}, a6 = {0,0,0,0}, a7 = {0,0,0,0};
        #define MM2C(vv, ch) { const float* _wb = &smem[W2L + (ch) * 32]; \
            FMA4(a0, vv, _wb + 0)  FMA4(a1, vv, _wb + 4)  FMA4(a2, vv, _wb + 8)  FMA4(a3, vv, _wb + 12) \
            FMA4(a4, vv, _wb + 16) FMA4(a5, vv, _wb + 20) FMA4(a6, vv, _wb + 24) FMA4(a7, vv, _wb + 28) }
        #pragma unroll
        for (int k4 = 0; k4 < 8; ++k4) {
            const float4 v = *(const float4*)&smem[S1O + (k4 * S1N + n) * 4];
            MM2C(v.x, 4 * k4 + 0)
            MM2C(v.y, 4 * k4 + 1)
            MM2C(v.z, 4 * k4 + 2)
            MM2C(v.w, 4 * k4 + 3)
        }
        #define ACT(aq, q) { const float4 _bb = *(const float4*)&b2[4 * (q)]; \
            aq.x = d * fmaxf(d * aq.x + _bb.x, 0.f); \
            aq.y = d * fmaxf(d * aq.y + _bb.y, 0.f); \
            aq.z = d * fmaxf(d * aq.z + _bb.z, 0.f); \
            aq.w = d * fmaxf(d * aq.w + _bb.w, 0.f); }
        ACT(a0,0) ACT(a1,1) ACT(a2,2) ACT(a3,3) ACT(a4,4) ACT(a5,5) ACT(a6,6) ACT(a7,7)
        float4 t0 = {0,0,0,0}, t1 = {0,0,0,0}, t2 = {0,0,0,0};
        #define MM3C(gv, ch) { const float* _wb = &smem[W3L + (ch) * 12]; \
            FMA4(t0, gv, _wb + 0) FMA4(t1, gv, _wb + 4) FMA4(t2, gv, _wb + 8) }
        #define MM3Q(aq, q) MM3C(aq.x, 4*(q)+0) MM3C(aq.y, 4*(q)+1) MM3C(aq.z, 4*(q)+2) MM3C(aq.w, 4*(q)+3)
        MM3Q(a0,0) MM3Q(a1,1) MM3Q(a2,2) MM3Q(a3,3) MM3Q(a4,4) MM3Q(a5,5) MM3Q(a6,6) MM3Q(a7,7)
        *(float4*)&smem[TBO + (0 * S1N + n) * 4] = t0;
        *(float4*)&smem[TBO + (1 * S1N + n) * 4] = t1;
        *(float4*)&smem[TBO + (2 * S1N + n) * 4] = t2;
    }
    __syncthreads();

    // ====== bs3 + epilogue: out = dinv*boxsum(t) + b3 -> outbuf [256][12] ======
    #pragma unroll
    for (int p = 0; p < 3; ++p) {
        for (int n = tid; n < ON; n += NT) {
            int li = n >> 4, lj = n & 15;
            int src = li * R3 + lj;
            float4 s = {0.f, 0.f, 0.f, 0.f};
            #pragma unroll
            for (int di = 0; di < 3; ++di)
                #pragma unroll
                for (int dj = 0; dj < 3; ++dj)
                    add4(s, *(const float4*)&smem[TBO + (p * S1N + src + di * R3 + dj) * 4]);
            float d = smem[DOO + n];
            float4 bb;
            if (p == 0)      bb = *(const float4*)&b3[0];
            else if (p == 1) bb = *(const float4*)&b3[4];
            else             bb = make_float4(b3[8], 0.f, 0.f, 0.f);
            float4 o;
            o.x = d * s.x + bb.x; o.y = d * s.y + bb.y;
            o.z = d * s.z + bb.z; o.w = d * s.w + bb.w;
            *(float4*)&smem[OUTB + n * 12 + 4 * p] = o;
        }
    }
    __syncthreads();

    // ====== pixel-shuffle write, float4 global stores ======
    for (int q = tid; q < ON * 9 / 4; q += NT) {    // 576
        int rr = q / 12, cc0 = 4 * (q % 12);
        int ii = rr / 3, si = rr % 3;
        float4 o;
        { int cc = cc0 + 0, jj = cc / 3, sj = cc % 3; o.x = smem[OUTB + (ii * TILE + jj) * 12 + si * 3 + sj]; }
        { int cc = cc0 + 1, jj = cc / 3, sj = cc % 3; o.y = smem[OUTB + (ii * TILE + jj) * 12 + si * 3 + sj]; }
        { int cc = cc0 + 2, jj = cc / 3, sj = cc % 3; o.z = smem[OUTB + (ii * TILE + jj) * 12 + si * 3 + sj]; }
        { int cc = cc0 + 3, jj = cc / 3, sj = cc % 3; o.w = smem[OUTB + (ii * TILE + jj) * 12 + si * 3 + sj]; }
        *(float4*)&out[(size_t)(oi * SS + rr) * (HH * SS) + oj * SS + cc0] = o;
    }
}

extern "C" void kernel_launch(void* const* d_in, const int* in_sizes, int n_in,
                              void* d_out, int out_size, void* d_ws, size_t ws_size,
                              hipStream_t stream) {
    const float* x  = (const float*)d_in[0];
    // d_in[1] = edge_index (int32) — fixed grid; derived analytically.
    const float* W1 = (const float*)d_in[2];
    const float* b1 = (const float*)d_in[3];
    const float* W2 = (const float*)d_in[4];
    const float* b2 = (const float*)d_in[5];
    const float* W3 = (const float*)d_in[6];
    const float* b3 = (const float*)d_in[7];
    float* out = (float*)d_out;

    dim3 grid(NB * NB), block(NT);
    gnn_fused<<<grid, block, 0, stream>>>(x, W1, b1, W2, b2, W3, b3, out);
}

// Round 4
// 97.782 us; speedup vs baseline: 11.7752x; 1.0310x over previous
//
#include <hip/hip_runtime.h>

// SatelliteImageGNN: 3-layer GCN on a 768x768 8-neighbor grid + pixel shuffle.
// layer = dinv * boxsum3x3(dinv .* h) @ W + b ; dinv from position (edge_index unused).
// Round-4: S1 buffer eliminated -> mm2 K-split (2 halves of 16 ch) accumulating in
// NAMED registers across barriers (no arrays, no runtime indexing -> no scratch).
// LDS 54.1 KB -> exactly 3 blocks/CU -> 2304 blocks = exactly 3.0 rounds, 24 waves/CU.

constexpr int HH = 768, SS = 3, TILE = 16, NB = 48, NT = 512;
constexpr int R1 = 22, R3 = 18;
constexpr int N1 = 484;            // 22x22 g0 domain
constexpr int S0N = 440;           // 20 rows x stride 22 (cols 20,21 junk, masked by D2=0)
constexpr int S1N = 324;           // 18x18
constexpr int ON  = 256;           // 16x16

// ---- LDS float offsets ----
constexpr int G0O  = 0;            // 486*4 = 1944 (484 + 2 zero-pad nodes)
constexpr int S0O  = 1944;         // 440*4 = 1760            [ends 3704]
constexpr int G1HO = 3888;         // 4 quad-planes * 440*4 = 7040  [ends 10928]
constexpr int D2O  = 10928;        // 440
constexpr int D3O  = 11368;        // 324
constexpr int DOO  = 11692;        // 256
constexpr int W1L  = 11948;        // 96   [3][32]
constexpr int W2L  = 12044;        // 1024 [32][32]
constexpr int W3L  = 13068;        // 384  [32][12] (cols 9..11 zero)
constexpr int B1L  = 13452;        // 32
constexpr int B2L  = 13484;        // 32
constexpr int B3L  = 13516;        // 12 (9 + zero pad)
constexpr int SMEMF= 13528;        // 54,112 B -> 3 blocks/CU (40,960 < sz <= 54,613)

constexpr int TBO  = 0;            // t: 3*324*4 = 3888, overlays G0+S0+pad (dead by then)
constexpr int OUTB = 4096;         // outbuf planar [3][256][4] = 3072, overlays G1H (dead)

__device__ __forceinline__ float dinv_of(int gi, int gj) {
    int e = (1 + (gi > 0) + (gi < HH - 1)) * (1 + (gj > 0) + (gj < HH - 1));
    return e == 9 ? 0.33333334f : (e == 6 ? 0.40824829f : 0.5f);
}
__device__ __forceinline__ void add4(float4& a, const float4 v) {
    a.x += v.x; a.y += v.y; a.z += v.z; a.w += v.w;
}
#define FMA4(acc, s, ptr) { const float4 _w = *(const float4*)(ptr); \
    acc.x += (s) * _w.x; acc.y += (s) * _w.y; acc.z += (s) * _w.z; acc.w += (s) * _w.w; }

__global__ __launch_bounds__(NT) void gnn_fused(
    const float* __restrict__ x,
    const float* __restrict__ W1, const float* __restrict__ b1,
    const float* __restrict__ W2, const float* __restrict__ b2,
    const float* __restrict__ W3, const float* __restrict__ b3,
    float* __restrict__ out)
{
    __shared__ __align__(16) float smem[SMEMF];
    const int tid = threadIdx.x;
    const int bi = blockIdx.x / NB;
    const int bj = blockIdx.x % NB;
    const int oi = bi * TILE, oj = bj * TILE;

    // ================= phase 0: stage weights + g0 + dinv planes =================
    for (int i = tid; i < 1024; i += NT) smem[W2L + i] = W2[i];
    for (int i = tid; i < 384;  i += NT) {
        int r = i / 12, c = i - r * 12;
        smem[W3L + i] = (c < 9) ? W3[r * 9 + c] : 0.f;
    }
    for (int i = tid; i < 96; i += NT) smem[W1L + i] = W1[i];
    if (tid < 32) { smem[B1L + tid] = b1[tid]; smem[B2L + tid] = b2[tid]; }
    if (tid < 12) smem[B3L + tid] = (tid < 9) ? b3[tid] : 0.f;

    if (tid < 486) {                       // g0 = dinv .* x on 22x22 (+2 zero pad)
        float4 v = {0.f, 0.f, 0.f, 0.f};
        if (tid < N1) {
            int li = tid / 22, lj = tid - li * 22;
            int gi = oi - 3 + li, gj = oj - 3 + lj;
            if ((unsigned)gi < HH && (unsigned)gj < HH) {
                float d = dinv_of(gi, gj);
                const float* xp = x + 3 * ((size_t)gi * HH + gj);
                v.x = d * xp[0]; v.y = d * xp[1]; v.z = d * xp[2];
            }
        }
        *(float4*)&smem[G0O + tid * 4] = v;
    }
    if (tid < S0N) {                       // dinv on R2 domain (0 = junk col / out-of-grid)
        int li = tid / 22, lj = tid - li * 22;
        int gi = oi - 2 + li, gj = oj - 2 + lj;
        float v = 0.f;
        if (lj < 20 && (unsigned)gi < HH && (unsigned)gj < HH) v = dinv_of(gi, gj);
        smem[D2O + tid] = v;
    }
    if (tid < S1N) {                       // dinv on R3 domain
        int li = tid / 18, lj = tid - li * 18;
        int gi = oi - 1 + li, gj = oj - 1 + lj;
        float v = 0.f;
        if ((unsigned)gi < HH && (unsigned)gj < HH) v = dinv_of(gi, gj);
        smem[D3O + tid] = v;
    }
    if (tid < ON) smem[DOO + tid] = dinv_of(oi + (tid >> 4), oj + (tid & 15));
    __syncthreads();

    // ================= bs1: s0 = boxsum(g0), 3 ch =================
    if (tid < S0N) {
        float4 s = {0.f, 0.f, 0.f, 0.f};
        #pragma unroll
        for (int di = 0; di < 3; ++di)
            #pragma unroll
            for (int dj = 0; dj < 3; ++dj)
                add4(s, *(const float4*)&smem[G0O + (tid + di * R1 + dj) * 4]);
        *(float4*)&smem[S0O + tid * 4] = s;
    }
    __syncthreads();

    // ---- fused-node coordinates (tid<324) ----
    const int fli = tid / 18, flj = tid - fli * 18;
    const int fbase = fli * R1 + flj;

    float4 a0 = {0,0,0,0}, a1 = {0,0,0,0}, a2 = {0,0,0,0}, a3 = {0,0,0,0};
    float4 a4 = {0,0,0,0}, a5 = {0,0,0,0}, a6 = {0,0,0,0}, a7 = {0,0,0,0};

    #define MM1_PHASE(H) \
        for (int item = tid; item < 4 * S0N; item += NT) { \
            int p = item / S0N, n = item - p * S0N; \
            int qq = 4 * (H) + p; \
            float d = smem[D2O + n]; \
            float4 s = *(const float4*)&smem[S0O + n * 4]; \
            float4 a = {0.f, 0.f, 0.f, 0.f}; \
            FMA4(a, s.x, &smem[W1L + 0 * 32 + 4 * qq]) \
            FMA4(a, s.y, &smem[W1L + 1 * 32 + 4 * qq]) \
            FMA4(a, s.z, &smem[W1L + 2 * 32 + 4 * qq]) \
            const float4 bb = *(const float4*)&smem[B1L + 4 * qq]; \
            float4 g; \
            g.x = d * fmaxf(d * a.x + bb.x, 0.f); \
            g.y = d * fmaxf(d * a.y + bb.y, 0.f); \
            g.z = d * fmaxf(d * a.z + bb.z, 0.f); \
            g.w = d * fmaxf(d * a.w + bb.w, 0.f); \
            *(float4*)&smem[G1HO + item * 4] = g; \
        }

    #define MM2C(vv, ch) { const float* _wb = &smem[W2L + (ch) * 32]; \
        FMA4(a0, vv, _wb + 0)  FMA4(a1, vv, _wb + 4)  FMA4(a2, vv, _wb + 8)  FMA4(a3, vv, _wb + 12) \
        FMA4(a4, vv, _wb + 16) FMA4(a5, vv, _wb + 20) FMA4(a6, vv, _wb + 24) FMA4(a7, vv, _wb + 28) }

    #define BS2MM2_HALF(H) \
        if (tid < S1N) { \
            _Pragma("unroll") \
            for (int p = 0; p < 4; ++p) { \
                float4 s1q = {0.f, 0.f, 0.f, 0.f}; \
                _Pragma("unroll") \
                for (int di = 0; di < 3; ++di) \
                    _Pragma("unroll") \
                    for (int dj = 0; dj < 3; ++dj) \
                        add4(s1q, *(const float4*)&smem[G1HO + (p * S0N + fbase + di * R1 + dj) * 4]); \
                MM2C(s1q.x, 16 * (H) + 4 * p + 0) \
                MM2C(s1q.y, 16 * (H) + 4 * p + 1) \
                MM2C(s1q.z, 16 * (H) + 4 * p + 2) \
                MM2C(s1q.w, 16 * (H) + 4 * p + 3) \
            } \
        }

    // ---- half 0 ----
    MM1_PHASE(0)
    __syncthreads();
    BS2MM2_HALF(0)
    __syncthreads();
    // ---- half 1 ----
    MM1_PHASE(1)
    __syncthreads();
    BS2MM2_HALF(1)

    // ---- act + mm3 fused (per-thread, no barrier needed before) ----
    if (tid < S1N) {
        const float d = smem[D3O + tid];
        #define ACT(aq, q) { const float4 _bb = *(const float4*)&smem[B2L + 4 * (q)]; \
            aq.x = d * fmaxf(d * aq.x + _bb.x, 0.f); \
            aq.y = d * fmaxf(d * aq.y + _bb.y, 0.f); \
            aq.z = d * fmaxf(d * aq.z + _bb.z, 0.f); \
            aq.w = d * fmaxf(d * aq.w + _bb.w, 0.f); }
        ACT(a0,0) ACT(a1,1) ACT(a2,2) ACT(a3,3) ACT(a4,4) ACT(a5,5) ACT(a6,6) ACT(a7,7)
        float4 t0 = {0,0,0,0}, t1 = {0,0,0,0}, t2 = {0,0,0,0};
        #define MM3C(gv, ch) { const float* _wb = &smem[W3L + (ch) * 12]; \
            FMA4(t0, gv, _wb + 0) FMA4(t1, gv, _wb + 4) FMA4(t2, gv, _wb + 8) }
        #define MM3Q(aq, q) MM3C(aq.x, 4*(q)+0) MM3C(aq.y, 4*(q)+1) MM3C(aq.z, 4*(q)+2) MM3C(aq.w, 4*(q)+3)
        MM3Q(a0,0) MM3Q(a1,1) MM3Q(a2,2) MM3Q(a3,3) MM3Q(a4,4) MM3Q(a5,5) MM3Q(a6,6) MM3Q(a7,7)
        *(float4*)&smem[TBO + (0 * S1N + tid) * 4] = t0;
        *(float4*)&smem[TBO + (1 * S1N + tid) * 4] = t1;
        *(float4*)&smem[TBO + (2 * S1N + tid) * 4] = t2;
    }
    __syncthreads();

    // ====== bs3 + epilogue: outbuf[p][n] = dinv*boxsum(t)[4p..] + b3 (planar) ======
    for (int item = tid; item < 3 * ON; item += NT) {
        int p = item >> 8, n = item & 255;
        int src = (n >> 4) * R3 + (n & 15);
        float4 s = {0.f, 0.f, 0.f, 0.f};
        #pragma unroll
        for (int di = 0; di < 3; ++di)
            #pragma unroll
            for (int dj = 0; dj < 3; ++dj)
                add4(s, *(const float4*)&smem[TBO + (p * S1N + src + di * R3 + dj) * 4]);
        float d = smem[DOO + n];
        float4 bb = *(const float4*)&smem[B3L + 4 * p];
        float4 o;
        o.x = d * s.x + bb.x; o.y = d * s.y + bb.y;
        o.z = d * s.z + bb.z; o.w = d * s.w + bb.w;
        *(float4*)&smem[OUTB + (p * ON + n) * 4] = o;
    }
    __syncthreads();

    // ====== pixel-shuffle write, float4 global stores ======
    for (int q = tid; q < ON * 9 / 4; q += NT) {    // 576
        int rr = q / 12, cc0 = 4 * (q % 12);
        int ii = rr / 3, si = rr - 3 * ii;
        float4 o;
        { int cc = cc0 + 0, jj = cc / 3, sj = cc - 3 * jj; int c = si * 3 + sj;
          o.x = smem[OUTB + ((c >> 2) * ON + ii * TILE + jj) * 4 + (c & 3)]; }
        { int cc = cc0 + 1, jj = cc / 3, sj = cc - 3 * jj; int c = si * 3 + sj;
          o.y = smem[OUTB + ((c >> 2) * ON + ii * TILE + jj) * 4 + (c & 3)]; }
        { int cc = cc0 + 2, jj = cc / 3, sj = cc - 3 * jj; int c = si * 3 + sj;
          o.z = smem[OUTB + ((c >> 2) * ON + ii * TILE + jj) * 4 + (c & 3)]; }
        { int cc = cc0 + 3, jj = cc / 3, sj = cc - 3 * jj; int c = si * 3 + sj;
          o.w = smem[OUTB + ((c >> 2) * ON + ii * TILE + jj) * 4 + (c & 3)]; }
        *(float4*)&out[(size_t)(oi * SS + rr) * (HH * SS) + oj * SS + cc0] = o;
    }
}

extern "C" void kernel_launch(void* const* d_in, const int* in_sizes, int n_in,
                              void* d_out, int out_size, void* d_ws, size_t ws_size,
                              hipStream_t stream) {
    const float* x  = (const float*)d_in[0];
    // d_in[1] = edge_index (int32) — fixed grid; derived analytically.
    const float* W1 = (const float*)d_in[2];
    const float* b1 = (const float*)d_in[3];
    const float* W2 = (const float*)d_in[4];
    const float* b2 = (const float*)d_in[5];
    const float* W3 = (const float*)d_in[6];
    const float* b3 = (const float*)d_in[7];
    float* out = (float*)d_out;

    dim3 grid(NB * NB), block(NT);
    gnn_fused<<<grid, block, 0, stream>>>(x, W1, b1, W2, b2, W3, b3, out);
}

// Round 5
// 73.223 us; speedup vs baseline: 15.7245x; 1.3354x over previous
//
#include <hip/hip_runtime.h>

// SatelliteImageGNN: 3-layer GCN on a 768x768 8-neighbor grid + pixel shuffle.
// layer = dinv * boxsum3x3(dinv .* h) @ W + b ; dinv from position (edge_index unused).
// Round-5: ALL weights/biases read from global with wave-uniform compile-time
// offsets -> s_load into SGPRs (scalar pipe). Removes ~350 broadcast ds_read_b128
// per thread from the heavy phase (round-4 was LDS-issue-bound at ~26k cyc/block).
// LDS 47.1 KB -> 3 blocks/CU; mm2 accumulators in named registers (no scratch).

constexpr int HH = 768, SS = 3, TILE = 16, NB = 48, NT = 512;
constexpr int R1 = 22, R3 = 18;
constexpr int N1  = 484;           // 22x22 g0 domain
constexpr int S0N = 440;           // 20 rows x stride 22 (junk cols masked via D2=0)
constexpr int S1N = 324;           // 18x18
constexpr int ON  = 256;           // 16x16

// ---- LDS float offsets ----
constexpr int G0O  = 0;            // 486*4 = 1944 (484 + 2 zero-pad nodes)
constexpr int S0O  = 1944;         // 440*4 = 1760              [ends 3704]
constexpr int G1HO = 3704;         // 4 quad-planes * 440*4 = 7040  [ends 10744]
constexpr int D2O  = 10744;        // 440
constexpr int D3O  = 11184;        // 324
constexpr int DOO  = 11508;        // 256
constexpr int SMEMF= 11764;        // 47,056 B -> 3 blocks/CU

// overlays (all dead-region checked):
constexpr int TB0  = 0;            // t plane0 float4: 324*4 = 1296   (over G0, dead)
constexpr int TB1  = 1296;         // t plane1 float4: 1296            (over G0/S0, dead)
constexpr int TB2  = 2592;         // t plane2 scalar: 324 -> ends 2916 (< 3704, no G1H clash)
constexpr int OUTB0= 3904;         // out plane0 [256][4] = 1024  (over G1H, dead)
constexpr int OUTB1= 4928;         // out plane1 [256][4] = 1024
constexpr int OUTB2= 5952;         // out plane2 scalar [256] -> ends 6208

__device__ __forceinline__ float dinv_of(int gi, int gj) {
    int e = (1 + (gi > 0) + (gi < HH - 1)) * (1 + (gj > 0) + (gj < HH - 1));
    return e == 9 ? 0.33333334f : (e == 6 ? 0.40824829f : 0.5f);
}
__device__ __forceinline__ void add4(float4& a, const float4 v) {
    a.x += v.x; a.y += v.y; a.z += v.z; a.w += v.w;
}
// weights from GLOBAL at uniform constant offsets -> s_load (scalar regs)
#define FMA4G(acc, s, wp) { const float4 _w = *(const float4*)(wp); \
    acc.x += (s) * _w.x; acc.y += (s) * _w.y; acc.z += (s) * _w.z; acc.w += (s) * _w.w; }
#define FMA4L(acc, s, ptr) { const float4 _w = *(const float4*)(ptr); \
    acc.x += (s) * _w.x; acc.y += (s) * _w.y; acc.z += (s) * _w.z; acc.w += (s) * _w.w; }

__global__ __launch_bounds__(NT) void gnn_fused(
    const float* __restrict__ x,
    const float* __restrict__ W1, const float* __restrict__ b1,
    const float* __restrict__ W2, const float* __restrict__ b2,
    const float* __restrict__ W3, const float* __restrict__ b3,
    float* __restrict__ out)
{
    __shared__ __align__(16) float smem[SMEMF];
    const int tid = threadIdx.x;
    const int bi = blockIdx.x / NB;
    const int bj = blockIdx.x % NB;
    const int oi = bi * TILE, oj = bj * TILE;

    // ================= phase 0: g0 + dinv planes (no weight staging) =================
    if (tid < 486) {
        float4 v = {0.f, 0.f, 0.f, 0.f};
        if (tid < N1) {
            int li = tid / 22, lj = tid - li * 22;
            int gi = oi - 3 + li, gj = oj - 3 + lj;
            if ((unsigned)gi < HH && (unsigned)gj < HH) {
                float d = dinv_of(gi, gj);
                const float* xp = x + 3 * ((size_t)gi * HH + gj);
                v.x = d * xp[0]; v.y = d * xp[1]; v.z = d * xp[2];
            }
        }
        *(float4*)&smem[G0O + tid * 4] = v;
    }
    if (tid < S0N) {
        int li = tid / 22, lj = tid - li * 22;
        int gi = oi - 2 + li, gj = oj - 2 + lj;
        float v = 0.f;
        if (lj < 20 && (unsigned)gi < HH && (unsigned)gj < HH) v = dinv_of(gi, gj);
        smem[D2O + tid] = v;
    }
    if (tid < S1N) {
        int li = tid / 18, lj = tid - li * 18;
        int gi = oi - 1 + li, gj = oj - 1 + lj;
        float v = 0.f;
        if ((unsigned)gi < HH && (unsigned)gj < HH) v = dinv_of(gi, gj);
        smem[D3O + tid] = v;
    }
    if (tid < ON) smem[DOO + tid] = dinv_of(oi + (tid >> 4), oj + (tid & 15));
    __syncthreads();

    // ================= bs1: s0 = boxsum(g0), 3 ch =================
    if (tid < S0N) {
        float4 s = {0.f, 0.f, 0.f, 0.f};
        #pragma unroll
        for (int di = 0; di < 3; ++di)
            #pragma unroll
            for (int dj = 0; dj < 3; ++dj)
                add4(s, *(const float4*)&smem[G0O + (tid + di * R1 + dj) * 4]);
        *(float4*)&smem[S0O + tid * 4] = s;
    }
    __syncthreads();

    // ---- fused-node coordinates (tid<324) ----
    const int fli = tid / 18, flj = tid - fli * 18;
    const int fbase = fli * R1 + flj;

    float4 a0 = {0,0,0,0}, a1 = {0,0,0,0}, a2 = {0,0,0,0}, a3 = {0,0,0,0};
    float4 a4 = {0,0,0,0}, a5 = {0,0,0,0}, a6 = {0,0,0,0}, a7 = {0,0,0,0};

    // mm1: channel-quad index qq is a compile-time constant -> W1/b1 s_loads
    #define MM1_PHASE(H) \
        if (tid < S0N) { \
            const float d = smem[D2O + tid]; \
            const float4 s = *(const float4*)&smem[S0O + tid * 4]; \
            _Pragma("unroll") \
            for (int p = 0; p < 4; ++p) { \
                const int qq = 4 * (H) + p; \
                float4 a = {0.f, 0.f, 0.f, 0.f}; \
                FMA4G(a, s.x, W1 + 0 * 32 + 4 * qq) \
                FMA4G(a, s.y, W1 + 1 * 32 + 4 * qq) \
                FMA4G(a, s.z, W1 + 2 * 32 + 4 * qq) \
                const float4 bb = *(const float4*)&b1[4 * qq]; \
                float4 g; \
                g.x = d * fmaxf(d * a.x + bb.x, 0.f); \
                g.y = d * fmaxf(d * a.y + bb.y, 0.f); \
                g.z = d * fmaxf(d * a.z + bb.z, 0.f); \
                g.w = d * fmaxf(d * a.w + bb.w, 0.f); \
                *(float4*)&smem[G1HO + (p * S0N + tid) * 4] = g; \
            } \
        }

    #define MM2C(vv, ch) { const float* _wb = W2 + (ch) * 32; \
        FMA4G(a0, vv, _wb + 0)  FMA4G(a1, vv, _wb + 4)  FMA4G(a2, vv, _wb + 8)  FMA4G(a3, vv, _wb + 12) \
        FMA4G(a4, vv, _wb + 16) FMA4G(a5, vv, _wb + 20) FMA4G(a6, vv, _wb + 24) FMA4G(a7, vv, _wb + 28) }

    #define BS2MM2_HALF(H) \
        if (tid < S1N) { \
            _Pragma("unroll") \
            for (int p = 0; p < 4; ++p) { \
                float4 s1q = {0.f, 0.f, 0.f, 0.f}; \
                _Pragma("unroll") \
                for (int di = 0; di < 3; ++di) \
                    _Pragma("unroll") \
                    for (int dj = 0; dj < 3; ++dj) \
                        add4(s1q, *(const float4*)&smem[G1HO + (p * S0N + fbase + di * R1 + dj) * 4]); \
                MM2C(s1q.x, 16 * (H) + 4 * p + 0) \
                MM2C(s1q.y, 16 * (H) + 4 * p + 1) \
                MM2C(s1q.z, 16 * (H) + 4 * p + 2) \
                MM2C(s1q.w, 16 * (H) + 4 * p + 3) \
            } \
        }

    MM1_PHASE(0)
    __syncthreads();
    BS2MM2_HALF(0)
    __syncthreads();
    MM1_PHASE(1)
    __syncthreads();
    BS2MM2_HALF(1)

    // ---- act + mm3 fused (per-thread; writes TB <= 2916 which no live reader touches) ----
    if (tid < S1N) {
        const float d = smem[D3O + tid];
        #define ACT(aq, q) { const float4 _bb = *(const float4*)&b2[4 * (q)]; \
            aq.x = d * fmaxf(d * aq.x + _bb.x, 0.f); \
            aq.y = d * fmaxf(d * aq.y + _bb.y, 0.f); \
            aq.z = d * fmaxf(d * aq.z + _bb.z, 0.f); \
            aq.w = d * fmaxf(d * aq.w + _bb.w, 0.f); }
        ACT(a0,0) ACT(a1,1) ACT(a2,2) ACT(a3,3) ACT(a4,4) ACT(a5,5) ACT(a6,6) ACT(a7,7)
        float4 t0 = {0,0,0,0}, t1 = {0,0,0,0};
        float  t2 = 0.f;
        #define MM3C(gv, ch) { const float* _w3 = W3 + (ch) * 9; \
            t0.x += (gv) * _w3[0]; t0.y += (gv) * _w3[1]; t0.z += (gv) * _w3[2]; t0.w += (gv) * _w3[3]; \
            t1.x += (gv) * _w3[4]; t1.y += (gv) * _w3[5]; t1.z += (gv) * _w3[6]; t1.w += (gv) * _w3[7]; \
            t2   += (gv) * _w3[8]; }
        #define MM3Q(aq, q) MM3C(aq.x, 4*(q)+0) MM3C(aq.y, 4*(q)+1) MM3C(aq.z, 4*(q)+2) MM3C(aq.w, 4*(q)+3)
        MM3Q(a0,0) MM3Q(a1,1) MM3Q(a2,2) MM3Q(a3,3) MM3Q(a4,4) MM3Q(a5,5) MM3Q(a6,6) MM3Q(a7,7)
        *(float4*)&smem[TB0 + tid * 4] = t0;
        *(float4*)&smem[TB1 + tid * 4] = t1;
        smem[TB2 + tid] = t2;
    }
    __syncthreads();

    // ====== bs3 + epilogue: out = dinv*boxsum(t) + b3, planar outbuf ======
    for (int item = tid; item < 3 * ON; item += NT) {
        int p = item >> 8, n = item & 255;
        int src = (n >> 4) * R3 + (n & 15);
        float d = smem[DOO + n];
        if (p == 2) {
            float s = 0.f;
            #pragma unroll
            for (int di = 0; di < 3; ++di)
                #pragma unroll
                for (int dj = 0; dj < 3; ++dj)
                    s += smem[TB2 + src + di * R3 + dj];
            smem[OUTB2 + n] = d * s + b3[8];
        } else {
            const int tb = p ? TB1 : TB0;
            float4 s = {0.f, 0.f, 0.f, 0.f};
            #pragma unroll
            for (int di = 0; di < 3; ++di)
                #pragma unroll
                for (int dj = 0; dj < 3; ++dj)
                    add4(s, *(const float4*)&smem[tb + (src + di * R3 + dj) * 4]);
            const float4 bb = *(const float4*)&b3[4 * p];
            float4 o;
            o.x = d * s.x + bb.x; o.y = d * s.y + bb.y;
            o.z = d * s.z + bb.z; o.w = d * s.w + bb.w;
            *(float4*)&smem[(p ? OUTB1 : OUTB0) + n * 4] = o;
        }
    }
    __syncthreads();

    // ====== pixel-shuffle write, float4 global stores ======
    #define ORD(n, c) ((c) < 8 ? smem[((c) < 4 ? OUTB0 : OUTB1) + (n) * 4 + ((c) & 3)] \
                               : smem[OUTB2 + (n)])
    for (int q = tid; q < ON * 9 / 4; q += NT) {    // 576
        int rr = q / 12, cc0 = 4 * (q % 12);
        int ii = rr / 3, si = rr - 3 * ii;
        float4 o;
        { int cc = cc0 + 0, jj = cc / 3, sj = cc - 3 * jj; o.x = ORD(ii * TILE + jj, si * 3 + sj); }
        { int cc = cc0 + 1, jj = cc / 3, sj = cc - 3 * jj; o.y = ORD(ii * TILE + jj, si * 3 + sj); }
        { int cc = cc0 + 2, jj = cc / 3, sj = cc - 3 * jj; o.z = ORD(ii * TILE + jj, si * 3 + sj); }
        { int cc = cc0 + 3, jj = cc / 3, sj = cc - 3 * jj; o.w = ORD(ii * TILE + jj, si * 3 + sj); }
        *(float4*)&out[(size_t)(oi * SS + rr) * (HH * SS) + oj * SS + cc0] = o;
    }
}

extern "C" void kernel_launch(void* const* d_in, const int* in_sizes, int n_in,
                              void* d_out, int out_size, void* d_ws, size_t ws_size,
                              hipStream_t stream) {
    const float* x  = (const float*)d_in[0];
    // d_in[1] = edge_index (int32) — fixed grid; derived analytically.
    const float* W1 = (const float*)d_in[2];
    const float* b1 = (const float*)d_in[3];
    const float* W2 = (const float*)d_in[4];
    const float* b2 = (const float*)d_in[5];
    const float* W3 = (const float*)d_in[6];
    const float* b3 = (const float*)d_in[7];
    float* out = (float*)d_out;

    dim3 grid(NB * NB), block(NT);
    gnn_fused<<<grid, block, 0, stream>>>(x, W1, b1, W2, b2, W3, b3, out);
}

// Round 6
// 61.868 us; speedup vs baseline: 18.6106x; 1.1835x over previous
//
#include <hip/hip_runtime.h>

// SatelliteImageGNN: 3-layer GCN on a 768x768 8-neighbor grid + pixel shuffle.
// layer = dinv * boxsum3x3(dinv .* h) @ W + b ; dinv from position (edge_index unused).
// Round-6: 12x32 output tile -> heavy-phase domain 14x34=476 ~= 93% of 512 threads
// (was 324/512=63%). G1 ping-pong single-quad buffers: each phase = bs2+mm2(q) on
// 476 threads + mm1(q+1) on all threads. Weights via SGPR (s_load). LDS 44.4 KB ->
// 3 blocks/CU; grid 1536 = exactly 2.0 rounds. Accumulators in named registers.

constexpr int HH = 768, SS = 3;
constexpr int TI = 12, TJ = 32;          // output tile
constexpr int NBJ = 24;                  // 768/TJ
constexpr int NT = 512;

constexpr int G0C = 38;                  // g0: 18 rows x 38 cols, origin (-3,-3)
constexpr int N0  = 684;
constexpr int S0C = 36;                  // s0/g1: 16 x 36, origin (-2,-2)
constexpr int NS0 = 576;
constexpr int R3C = 34;                  // h2/t: 14 x 34, origin (-1,-1)
constexpr int NS1 = 476;
constexpr int ON  = 384;                 // 12*32

// ---- LDS float offsets ----
constexpr int G0O = 0;                   // 688*4 = 2752 (684 + 4 pad)
constexpr int S0O = 2752;                // 576*4 = 2304
constexpr int G1A = 5056;                // 576*4 = 2304 (quad ping)
constexpr int G1B = 7360;                // 576*4 = 2304 (quad pong)
constexpr int D2O = 9664;                // 576
constexpr int D3O = 10240;               // 476
constexpr int DOO = 10716;               // 384
constexpr int SMEMF = 11100;             // 44,400 B -> 3 blocks/CU

// overlays (dead-region checked):
constexpr int TB0 = 0;                   // t plane0: 476*4 = 1904 (over G0, dead)
constexpr int TB1 = 1904;                // t plane1: 1904 -> 3808 (over G0/S0, dead)
constexpr int TB2 = 3808;                // t plane2 scalar: 476 -> 4284 (< G1A) ok
constexpr int OUTB0 = 5056;              // out plane0 [384][4] (over G1A, dead)
constexpr int OUTB1 = 6592;              // out plane1 [384][4]
constexpr int OUTB2 = 8128;              // out plane2 scalar -> 8512 (< D2O) ok

__device__ __forceinline__ float dinv_of(int gi, int gj) {
    int e = (1 + (gi > 0) + (gi < HH - 1)) * (1 + (gj > 0) + (gj < HH - 1));
    return e == 9 ? 0.33333334f : (e == 6 ? 0.40824829f : 0.5f);
}
__device__ __forceinline__ void add4(float4& a, const float4 v) {
    a.x += v.x; a.y += v.y; a.z += v.z; a.w += v.w;
}
// weights read from GLOBAL at wave-uniform compile-time offsets -> s_load (SGPRs)
#define FMA4G(acc, s, wp) { const float4 _w = *(const float4*)(wp); \
    acc.x += (s) * _w.x; acc.y += (s) * _w.y; acc.z += (s) * _w.z; acc.w += (s) * _w.w; }

__global__ __launch_bounds__(NT) void gnn_fused(
    const float* __restrict__ x,
    const float* __restrict__ W1, const float* __restrict__ b1,
    const float* __restrict__ W2, const float* __restrict__ b2,
    const float* __restrict__ W3, const float* __restrict__ b3,
    float* __restrict__ out)
{
    __shared__ __align__(16) float smem[SMEMF];
    const int tid = threadIdx.x;
    const int bi = blockIdx.x / NBJ;
    const int bj = blockIdx.x % NBJ;
    const int oi = bi * TI, oj = bj * TJ;

    // ================= phase 0: g0 + dinv planes =================
    for (int n = tid; n < 688; n += NT) {
        float4 v = {0.f, 0.f, 0.f, 0.f};
        if (n < N0) {
            int li = n / G0C, lj = n - li * G0C;
            int gi = oi - 3 + li, gj = oj - 3 + lj;
            if ((unsigned)gi < HH && (unsigned)gj < HH) {
                float d = dinv_of(gi, gj);
                const float* xp = x + 3 * ((size_t)gi * HH + gj);
                v.x = d * xp[0]; v.y = d * xp[1]; v.z = d * xp[2];
            }
        }
        *(float4*)&smem[G0O + n * 4] = v;
    }
    for (int n = tid; n < NS0; n += NT) {
        int li = n / S0C, lj = n - li * S0C;
        int gi = oi - 2 + li, gj = oj - 2 + lj;
        smem[D2O + n] = ((unsigned)gi < HH && (unsigned)gj < HH) ? dinv_of(gi, gj) : 0.f;
    }
    if (tid < NS1) {
        int li = tid / R3C, lj = tid - li * R3C;
        int gi = oi - 1 + li, gj = oj - 1 + lj;
        smem[D3O + tid] = ((unsigned)gi < HH && (unsigned)gj < HH) ? dinv_of(gi, gj) : 0.f;
    }
    if (tid < ON) smem[DOO + tid] = dinv_of(oi + (tid >> 5), oj + (tid & 31));
    __syncthreads();

    // ================= bs1: s0 = boxsum(g0), 3 ch =================
    for (int n = tid; n < NS0; n += NT) {
        int li = n / S0C, lj = n - li * S0C;
        int base = li * G0C + lj;
        float4 s = {0.f, 0.f, 0.f, 0.f};
        #pragma unroll
        for (int di = 0; di < 3; ++di)
            #pragma unroll
            for (int dj = 0; dj < 3; ++dj)
                add4(s, *(const float4*)&smem[G0O + (base + di * G0C + dj) * 4]);
        *(float4*)&smem[S0O + n * 4] = s;
    }
    __syncthreads();

    // ---- heavy-phase node coordinates (tid < 476) ----
    const int fli = tid / R3C, flj = tid - fli * R3C;
    const int fbase = fli * S0C + flj;

    float4 a0 = {0,0,0,0}, a1 = {0,0,0,0}, a2 = {0,0,0,0}, a3 = {0,0,0,0};
    float4 a4 = {0,0,0,0}, a5 = {0,0,0,0}, a6 = {0,0,0,0}, a7 = {0,0,0,0};

    // mm1 for channel-quad q (compile-time) -> buffer BUF; all 512 threads
    #define MM1Q(q, BUF) \
        for (int n = tid; n < NS0; n += NT) { \
            const float d = smem[D2O + n]; \
            const float4 s = *(const float4*)&smem[S0O + n * 4]; \
            float4 a = {0.f, 0.f, 0.f, 0.f}; \
            FMA4G(a, s.x, W1 + 0 * 32 + 4 * (q)) \
            FMA4G(a, s.y, W1 + 1 * 32 + 4 * (q)) \
            FMA4G(a, s.z, W1 + 2 * 32 + 4 * (q)) \
            const float4 bb = *(const float4*)&b1[4 * (q)]; \
            float4 g; \
            g.x = d * fmaxf(d * a.x + bb.x, 0.f); \
            g.y = d * fmaxf(d * a.y + bb.y, 0.f); \
            g.z = d * fmaxf(d * a.z + bb.z, 0.f); \
            g.w = d * fmaxf(d * a.w + bb.w, 0.f); \
            *(float4*)&smem[(BUF) + n * 4] = g; \
        }

    #define MM2C(vv, ch) { const float* _wb = W2 + (ch) * 32; \
        FMA4G(a0, vv, _wb + 0)  FMA4G(a1, vv, _wb + 4)  FMA4G(a2, vv, _wb + 8)  FMA4G(a3, vv, _wb + 12) \
        FMA4G(a4, vv, _wb + 16) FMA4G(a5, vv, _wb + 20) FMA4G(a6, vv, _wb + 24) FMA4G(a7, vv, _wb + 28) }

    // bs2 (9-tap boxsum of g1 quad q) + mm2 partial accumulate; 476 threads
    #define BS2MM2Q(q, BUF) \
        if (tid < NS1) { \
            float4 s1q = {0.f, 0.f, 0.f, 0.f}; \
            _Pragma("unroll") \
            for (int di = 0; di < 3; ++di) \
                _Pragma("unroll") \
                for (int dj = 0; dj < 3; ++dj) \
                    add4(s1q, *(const float4*)&smem[(BUF) + (fbase + di * S0C + dj) * 4]); \
            MM2C(s1q.x, 4 * (q) + 0) \
            MM2C(s1q.y, 4 * (q) + 1) \
            MM2C(s1q.z, 4 * (q) + 2) \
            MM2C(s1q.w, 4 * (q) + 3) \
        }

    // ---- ping-pong pipeline over the 8 channel-quads ----
    MM1Q(0, G1A) __syncthreads();
    BS2MM2Q(0, G1A) MM1Q(1, G1B) __syncthreads();
    BS2MM2Q(1, G1B) MM1Q(2, G1A) __syncthreads();
    BS2MM2Q(2, G1A) MM1Q(3, G1B) __syncthreads();
    BS2MM2Q(3, G1B) MM1Q(4, G1A) __syncthreads();
    BS2MM2Q(4, G1A) MM1Q(5, G1B) __syncthreads();
    BS2MM2Q(5, G1B) MM1Q(6, G1A) __syncthreads();
    BS2MM2Q(6, G1A) MM1Q(7, G1B) __syncthreads();
    BS2MM2Q(7, G1B)

    // ---- act + mm3 fused (per-thread); t overlays G0/S0 (dead) ----
    if (tid < NS1) {
        const float d = smem[D3O + tid];
        #define ACT(aq, q) { const float4 _bb = *(const float4*)&b2[4 * (q)]; \
            aq.x = d * fmaxf(d * aq.x + _bb.x, 0.f); \
            aq.y = d * fmaxf(d * aq.y + _bb.y, 0.f); \
            aq.z = d * fmaxf(d * aq.z + _bb.z, 0.f); \
            aq.w = d * fmaxf(d * aq.w + _bb.w, 0.f); }
        ACT(a0,0) ACT(a1,1) ACT(a2,2) ACT(a3,3) ACT(a4,4) ACT(a5,5) ACT(a6,6) ACT(a7,7)
        float4 t0 = {0,0,0,0}, t1 = {0,0,0,0};
        float  t2 = 0.f;
        #define MM3C(gv, ch) { const float* _w3 = W3 + (ch) * 9; \
            t0.x += (gv) * _w3[0]; t0.y += (gv) * _w3[1]; t0.z += (gv) * _w3[2]; t0.w += (gv) * _w3[3]; \
            t1.x += (gv) * _w3[4]; t1.y += (gv) * _w3[5]; t1.z += (gv) * _w3[6]; t1.w += (gv) * _w3[7]; \
            t2   += (gv) * _w3[8]; }
        #define MM3Q(aq, q) MM3C(aq.x, 4*(q)+0) MM3C(aq.y, 4*(q)+1) MM3C(aq.z, 4*(q)+2) MM3C(aq.w, 4*(q)+3)
        MM3Q(a0,0) MM3Q(a1,1) MM3Q(a2,2) MM3Q(a3,3) MM3Q(a4,4) MM3Q(a5,5) MM3Q(a6,6) MM3Q(a7,7)
        *(float4*)&smem[TB0 + tid * 4] = t0;
        *(float4*)&smem[TB1 + tid * 4] = t1;
        smem[TB2 + tid] = t2;
    }
    __syncthreads();

    // ====== bs3 + epilogue: out = dinv*boxsum(t) + b3, planar outbuf ======
    for (int item = tid; item < 3 * ON; item += NT) {
        int p = item / ON, n = item - p * ON;
        int src = (n >> 5) * R3C + (n & 31);
        float d = smem[DOO + n];
        if (p == 2) {
            float s = 0.f;
            #pragma unroll
            for (int di = 0; di < 3; ++di)
                #pragma unroll
                for (int dj = 0; dj < 3; ++dj)
                    s += smem[TB2 + src + di * R3C + dj];
            smem[OUTB2 + n] = d * s + b3[8];
        } else {
            const int tb = p ? TB1 : TB0;
            float4 s = {0.f, 0.f, 0.f, 0.f};
            #pragma unroll
            for (int di = 0; di < 3; ++di)
                #pragma unroll
                for (int dj = 0; dj < 3; ++dj)
                    add4(s, *(const float4*)&smem[tb + (src + di * R3C + dj) * 4]);
            const float4 bb = *(const float4*)&b3[4 * p];
            float4 o;
            o.x = d * s.x + bb.x; o.y = d * s.y + bb.y;
            o.z = d * s.z + bb.z; o.w = d * s.w + bb.w;
            *(float4*)&smem[(p ? OUTB1 : OUTB0) + n * 4] = o;
        }
    }
    __syncthreads();

    // ====== pixel-shuffle write: 36 rows x 96 cols per block, float4 stores ======
    #define ORD(n, c) ((c) < 8 ? smem[((c) < 4 ? OUTB0 : OUTB1) + (n) * 4 + ((c) & 3)] \
                               : smem[OUTB2 + (n)])
    for (int q = tid; q < 36 * 24; q += NT) {      // 864 float4 stores
        int rr = q / 24, cc0 = 4 * (q % 24);
        int ii = rr / 3, si = rr - 3 * ii;
        float4 o;
        { int cc = cc0 + 0, jj = cc / 3, sj = cc - 3 * jj; o.x = ORD(ii * TJ + jj, si * 3 + sj); }
        { int cc = cc0 + 1, jj = cc / 3, sj = cc - 3 * jj; o.y = ORD(ii * TJ + jj, si * 3 + sj); }
        { int cc = cc0 + 2, jj = cc / 3, sj = cc - 3 * jj; o.z = ORD(ii * TJ + jj, si * 3 + sj); }
        { int cc = cc0 + 3, jj = cc / 3, sj = cc - 3 * jj; o.w = ORD(ii * TJ + jj, si * 3 + sj); }
        *(float4*)&out[(size_t)(oi * SS + rr) * (HH * SS) + oj * SS + cc0] = o;
    }
}

extern "C" void kernel_launch(void* const* d_in, const int* in_sizes, int n_in,
                              void* d_out, int out_size, void* d_ws, size_t ws_size,
                              hipStream_t stream) {
    const float* x  = (const float*)d_in[0];
    // d_in[1] = edge_index (int32) — fixed grid; derived analytically.
    const float* W1 = (const float*)d_in[2];
    const float* b1 = (const float*)d_in[3];
    const float* W2 = (const float*)d_in[4];
    const float* b2 = (const float*)d_in[5];
    const float* W3 = (const float*)d_in[6];
    const float* b3 = (const float*)d_in[7];
    float* out = (float*)d_out;

    dim3 grid(64 * NBJ), block(NT);
    gnn_fused<<<grid, block, 0, stream>>>(x, W1, b1, W2, b2, W3, b3, out);
}

// Round 7
// 51.119 us; speedup vs baseline: 22.5240x; 1.2103x over previous
//
#include <hip/hip_runtime.h>

// SatelliteImageGNN: 3-layer GCN on a 768x768 8-neighbor grid + pixel shuffle.
// layer = dinv * boxsum3x3(dinv .* h) @ W + b ; dinv from position (edge_index unused).
// Round-7: mm2/mm3 via v_dot2_f32_f16 (f16 pairs, fp32 accum; weights prepacked by a
// 1-block prekernel into a __device__ global); g1 stored packed-f16 in LDS (b64 taps,
// v_pk_add_f16 boxsum, 4-deep rounding tree); s0 + dinv in registers (S0/D2/D3/DOO
// LDS buffers deleted). Tile 12x32, grid 1536 = exactly 2 rounds at 3 blocks/CU.

constexpr int HH = 768, SS = 3;
constexpr int TI = 12, TJ = 32;
constexpr int NBJ = 24;                 // 768/TJ
constexpr int NT = 512;

constexpr int G0C = 38;                 // g0: 18 x 38, origin (-3,-3)
constexpr int N0  = 684;
constexpr int S0C = 36;                 // s0/g1 (L1): 16 x 36, origin (-2,-2)
constexpr int NS0 = 576;
constexpr int R3C = 34;                 // h2/t (L2): 14 x 34, origin (-1,-1)
constexpr int NS1 = 476;
constexpr int ON  = 384;                // 12*32

// ---- LDS float offsets ----
constexpr int G0O  = 0;                 // 684 float4 = 2736
constexpr int G1A  = 0;                 // 576 nodes x 2 floats (packed f16x4) = 1152 (over G0, dead)
constexpr int G1B  = 1152;              // 1152 -> 2304 (over G0, dead)
constexpr int TB0  = 0;                 // t plane0 f4: 476*4 = 1904 (over G1A, dead)
constexpr int TB1  = 1904;              // 1904 -> 3808 (over G1B, dead)
constexpr int TB2v = 3808;              // scalar 476 -> 4284
constexpr int OUT0 = 4288;              // [384][4] = 1536
constexpr int OUT1 = 5824;              // 1536
constexpr int OUT2 = 7360;              // 384 -> 7744
constexpr int SMEMF = 7744;             // 30,976 B

// packed f16 weights: [0,512) W2p[kp*32+o] (k-pair kp, out o); [512,704) W3p[kp*12+o] (o<9 used)
__device__ uint32_t g_wpack[704];

using h2 = decltype(__builtin_amdgcn_cvt_pkrtz(0.f, 0.f));

#if __has_builtin(__builtin_amdgcn_fdot2)
#define FDOT2(a, b, c) __builtin_amdgcn_fdot2((a), (b), (c), false)
#else
#define FDOT2(a, b, c) ((c) + (float)(a)[0] * (float)(b)[0] + (float)(a)[1] * (float)(b)[1])
#endif
#define PK(a, b) __builtin_amdgcn_cvt_pkrtz((a), (b))
#define BC2(u)   __builtin_bit_cast(h2, (u))

__device__ __forceinline__ h2 w2p(int kp, int o) { return BC2(g_wpack[kp * 32 + o]); }
__device__ __forceinline__ h2 w3p(int kp, int o) { return BC2(g_wpack[512 + kp * 12 + o]); }

__device__ __forceinline__ float dinv_of(int gi, int gj) {
    int e = (1 + (gi > 0) + (gi < HH - 1)) * (1 + (gj > 0) + (gj < HH - 1));
    return e == 9 ? 0.33333334f : (e == 6 ? 0.40824829f : 0.5f);
}
__device__ __forceinline__ void add4(float4& a, const float4 v) {
    a.x += v.x; a.y += v.y; a.z += v.z; a.w += v.w;
}
#define FMA4G(acc, s, wp) { const float4 _w = *(const float4*)(wp); \
    acc.x += (s) * _w.x; acc.y += (s) * _w.y; acc.z += (s) * _w.z; acc.w += (s) * _w.w; }

__global__ __launch_bounds__(NT) void pack_weights(const float* __restrict__ W2,
                                                   const float* __restrict__ W3) {
    int t = threadIdx.x;
    {   // W2p: pair of k-rows (2kp, 2kp+1), out column o
        int kp = t >> 5, o = t & 31;
        g_wpack[t] = __builtin_bit_cast(uint32_t, PK(W2[(2 * kp) * 32 + o], W2[(2 * kp + 1) * 32 + o]));
    }
    if (t < 192) {
        int kp = t / 12, o = t - kp * 12;
        float a = (o < 9) ? W3[(2 * kp) * 9 + o] : 0.f;
        float b = (o < 9) ? W3[(2 * kp + 1) * 9 + o] : 0.f;
        g_wpack[512 + t] = __builtin_bit_cast(uint32_t, PK(a, b));
    }
}

__global__ __launch_bounds__(NT) void gnn_fused(
    const float* __restrict__ x,
    const float* __restrict__ W1, const float* __restrict__ b1,
    const float* __restrict__ b2, const float* __restrict__ b3,
    float* __restrict__ out)
{
    __shared__ __align__(16) float smem[SMEMF];
    const int tid = threadIdx.x;
    const int bi = blockIdx.x / NBJ;
    const int bj = blockIdx.x % NBJ;
    const int oi = bi * TI, oj = bj * TJ;

    // ================= phase 0: stage g0 = dinv .* x (18x38) =================
    for (int n = tid; n < N0; n += NT) {
        int li = n / G0C, lj = n - li * G0C;
        int gi = oi - 3 + li, gj = oj - 3 + lj;
        float4 v = {0.f, 0.f, 0.f, 0.f};
        if ((unsigned)gi < HH && (unsigned)gj < HH) {
            float d = dinv_of(gi, gj);
            const float* xp = x + 3 * ((size_t)gi * HH + gj);
            v.x = d * xp[0]; v.y = d * xp[1]; v.z = d * xp[2];
        }
        *(float4*)&smem[G0O + n * 4] = v;
    }
    __syncthreads();

    // ============ phase 1: s0 + dinv into REGISTERS (own nodes only) ============
    // mm1 node A = tid (always), node B = tid+512 (tid<64). heavy node = tid (<476).
    float4 s0a = {0,0,0,0}, s0b = {0,0,0,0};
    float d2a = 0.f, d2b = 0.f, d3 = 0.f;
    {
        int li = tid / S0C, lj = tid - li * S0C;
        int base = li * G0C + lj;
        #pragma unroll
        for (int di = 0; di < 3; ++di)
            #pragma unroll
            for (int dj = 0; dj < 3; ++dj)
                add4(s0a, *(const float4*)&smem[G0O + (base + di * G0C + dj) * 4]);
        int gi = oi - 2 + li, gj = oj - 2 + lj;
        if ((unsigned)gi < HH && (unsigned)gj < HH) d2a = dinv_of(gi, gj);
    }
    if (tid < NS0 - NT) {
        int n = tid + NT;
        int li = n / S0C, lj = n - li * S0C;
        int base = li * G0C + lj;
        #pragma unroll
        for (int di = 0; di < 3; ++di)
            #pragma unroll
            for (int dj = 0; dj < 3; ++dj)
                add4(s0b, *(const float4*)&smem[G0O + (base + di * G0C + dj) * 4]);
        int gi = oi - 2 + li, gj = oj - 2 + lj;
        if ((unsigned)gi < HH && (unsigned)gj < HH) d2b = dinv_of(gi, gj);
    }
    const int fli = tid / R3C, flj = tid - fli * R3C;
    const int fbase = fli * S0C + flj;       // top-left L1 node of the 3x3 window
    if (tid < NS1) {
        int gi = oi - 1 + fli, gj = oj - 1 + flj;
        if ((unsigned)gi < HH && (unsigned)gj < HH) d3 = dinv_of(gi, gj);
    }
    __syncthreads();   // g0 now dead; G1A/G1B may overlay it

    float4 a0 = {0,0,0,0}, a1 = {0,0,0,0}, a2 = {0,0,0,0}, a3 = {0,0,0,0};
    float4 a4 = {0,0,0,0}, a5 = {0,0,0,0}, a6 = {0,0,0,0}, a7 = {0,0,0,0};

    // mm1 quad q from register s0 -> packed f16 write (1 ds_write_b64 per node)
    #define MM1Q(q, BUF) { \
        { float4 a = {0,0,0,0}; \
          FMA4G(a, s0a.x, W1 + 4 * (q)) FMA4G(a, s0a.y, W1 + 32 + 4 * (q)) FMA4G(a, s0a.z, W1 + 64 + 4 * (q)) \
          const float4 bb = *(const float4*)&b1[4 * (q)]; \
          float gx = d2a * fmaxf(d2a * a.x + bb.x, 0.f); \
          float gy = d2a * fmaxf(d2a * a.y + bb.y, 0.f); \
          float gz = d2a * fmaxf(d2a * a.z + bb.z, 0.f); \
          float gw = d2a * fmaxf(d2a * a.w + bb.w, 0.f); \
          uint2 u; u.x = __builtin_bit_cast(uint32_t, PK(gx, gy)); \
                   u.y = __builtin_bit_cast(uint32_t, PK(gz, gw)); \
          *(uint2*)&smem[(BUF) + tid * 2] = u; } \
        if (tid < NS0 - NT) { float4 a = {0,0,0,0}; \
          FMA4G(a, s0b.x, W1 + 4 * (q)) FMA4G(a, s0b.y, W1 + 32 + 4 * (q)) FMA4G(a, s0b.z, W1 + 64 + 4 * (q)) \
          const float4 bb = *(const float4*)&b1[4 * (q)]; \
          float gx = d2b * fmaxf(d2b * a.x + bb.x, 0.f); \
          float gy = d2b * fmaxf(d2b * a.y + bb.y, 0.f); \
          float gz = d2b * fmaxf(d2b * a.z + bb.z, 0.f); \
          float gw = d2b * fmaxf(d2b * a.w + bb.w, 0.f); \
          uint2 u; u.x = __builtin_bit_cast(uint32_t, PK(gx, gy)); \
                   u.y = __builtin_bit_cast(uint32_t, PK(gz, gw)); \
          *(uint2*)&smem[(BUF) + (tid + NT) * 2] = u; } \
    }

    #define MM2P(aq, ob) \
        aq.x = FDOT2(sl, w2p(kp0, (ob)+0), aq.x); aq.x = FDOT2(sh, w2p(kp1, (ob)+0), aq.x); \
        aq.y = FDOT2(sl, w2p(kp0, (ob)+1), aq.y); aq.y = FDOT2(sh, w2p(kp1, (ob)+1), aq.y); \
        aq.z = FDOT2(sl, w2p(kp0, (ob)+2), aq.z); aq.z = FDOT2(sh, w2p(kp1, (ob)+2), aq.z); \
        aq.w = FDOT2(sl, w2p(kp0, (ob)+3), aq.w); aq.w = FDOT2(sh, w2p(kp1, (ob)+3), aq.w);

    // bs2 (9x b64 taps, pk_add_f16 tree, 4-deep) + mm2 (64 fdot2); 476 threads
    #define BS2MM2Q(q, BUF) \
        if (tid < NS1) { \
            const int kp0 = 2 * (q), kp1 = 2 * (q) + 1; \
            const int _tb = (BUF) + fbase * 2; \
            const uint2 u00 = *(const uint2*)&smem[_tb +  0]; \
            const uint2 u01 = *(const uint2*)&smem[_tb +  2]; \
            const uint2 u02 = *(const uint2*)&smem[_tb +  4]; \
            const uint2 u10 = *(const uint2*)&smem[_tb + 2 * S0C + 0]; \
            const uint2 u11 = *(const uint2*)&smem[_tb + 2 * S0C + 2]; \
            const uint2 u12 = *(const uint2*)&smem[_tb + 2 * S0C + 4]; \
            const uint2 u20 = *(const uint2*)&smem[_tb + 4 * S0C + 0]; \
            const uint2 u21 = *(const uint2*)&smem[_tb + 4 * S0C + 2]; \
            const uint2 u22 = *(const uint2*)&smem[_tb + 4 * S0C + 4]; \
            h2 rl0 = (BC2(u00.x) + BC2(u01.x)) + BC2(u02.x); \
            h2 rl1 = (BC2(u10.x) + BC2(u11.x)) + BC2(u12.x); \
            h2 rl2 = (BC2(u20.x) + BC2(u21.x)) + BC2(u22.x); \
            h2 sl  = (rl0 + rl1) + rl2; \
            h2 rh0 = (BC2(u00.y) + BC2(u01.y)) + BC2(u02.y); \
            h2 rh1 = (BC2(u10.y) + BC2(u11.y)) + BC2(u12.y); \
            h2 rh2 = (BC2(u20.y) + BC2(u21.y)) + BC2(u22.y); \
            h2 sh  = (rh0 + rh1) + rh2; \
            MM2P(a0, 0) MM2P(a1, 4) MM2P(a2, 8)  MM2P(a3, 12) \
            MM2P(a4, 16) MM2P(a5, 20) MM2P(a6, 24) MM2P(a7, 28) \
        }

    // ---- ping-pong over 8 channel-quads ----
    MM1Q(0, G1A) __syncthreads();
    BS2MM2Q(0, G1A) MM1Q(1, G1B) __syncthreads();
    BS2MM2Q(1, G1B) MM1Q(2, G1A) __syncthreads();
    BS2MM2Q(2, G1A) MM1Q(3, G1B) __syncthreads();
    BS2MM2Q(3, G1B) MM1Q(4, G1A) __syncthreads();
    BS2MM2Q(4, G1A) MM1Q(5, G1B) __syncthreads();
    BS2MM2Q(5, G1B) MM1Q(6, G1A) __syncthreads();
    BS2MM2Q(6, G1A) MM1Q(7, G1B) __syncthreads();
    BS2MM2Q(7, G1B)
    __syncthreads();   // G1A/G1B dead; TB may overlay

    // ---- act + mm3 (fdot2, 144 inst) -> t planes in fp32 LDS ----
    if (tid < NS1) {
        const float d = d3;
        #define ACT(aq, q) { const float4 _bb = *(const float4*)&b2[4 * (q)]; \
            aq.x = d * fmaxf(d * aq.x + _bb.x, 0.f); \
            aq.y = d * fmaxf(d * aq.y + _bb.y, 0.f); \
            aq.z = d * fmaxf(d * aq.z + _bb.z, 0.f); \
            aq.w = d * fmaxf(d * aq.w + _bb.w, 0.f); }
        ACT(a0,0) ACT(a1,1) ACT(a2,2) ACT(a3,3) ACT(a4,4) ACT(a5,5) ACT(a6,6) ACT(a7,7)
        h2 p0 = PK(a0.x, a0.y), p1 = PK(a0.z, a0.w), p2  = PK(a1.x, a1.y), p3  = PK(a1.z, a1.w);
        h2 p4 = PK(a2.x, a2.y), p5 = PK(a2.z, a2.w), p6  = PK(a3.x, a3.y), p7  = PK(a3.z, a3.w);
        h2 p8 = PK(a4.x, a4.y), p9 = PK(a4.z, a4.w), p10 = PK(a5.x, a5.y), p11 = PK(a5.z, a5.w);
        h2 p12 = PK(a6.x, a6.y), p13 = PK(a6.z, a6.w), p14 = PK(a7.x, a7.y), p15 = PK(a7.z, a7.w);
        float4 t0 = {0,0,0,0}, t1 = {0,0,0,0};
        float t2 = 0.f;
        #define MM3KP(kp, pp) \
            t0.x = FDOT2(pp, w3p(kp,0), t0.x); t0.y = FDOT2(pp, w3p(kp,1), t0.y); \
            t0.z = FDOT2(pp, w3p(kp,2), t0.z); t0.w = FDOT2(pp, w3p(kp,3), t0.w); \
            t1.x = FDOT2(pp, w3p(kp,4), t1.x); t1.y = FDOT2(pp, w3p(kp,5), t1.y); \
            t1.z = FDOT2(pp, w3p(kp,6), t1.z); t1.w = FDOT2(pp, w3p(kp,7), t1.w); \
            t2   = FDOT2(pp, w3p(kp,8), t2);
        MM3KP(0,p0)  MM3KP(1,p1)  MM3KP(2,p2)   MM3KP(3,p3)
        MM3KP(4,p4)  MM3KP(5,p5)  MM3KP(6,p6)   MM3KP(7,p7)
        MM3KP(8,p8)  MM3KP(9,p9)  MM3KP(10,p10) MM3KP(11,p11)
        MM3KP(12,p12) MM3KP(13,p13) MM3KP(14,p14) MM3KP(15,p15)
        *(float4*)&smem[TB0 + tid * 4] = t0;
        *(float4*)&smem[TB1 + tid * 4] = t1;
        smem[TB2v + tid] = t2;
    }
    __syncthreads();

    // ====== bs3 + epilogue: out = dinv*boxsum(t) + b3 -> planar outbuf ======
    for (int item = tid; item < 3 * ON; item += NT) {
        int p = item / ON, n = item - p * ON;
        int li = n >> 5, lj = n & 31;
        int src = li * R3C + lj;
        float d = dinv_of(oi + li, oj + lj);
        if (p == 2) {
            float s = 0.f;
            #pragma unroll
            for (int di = 0; di < 3; ++di)
                #pragma unroll
                for (int dj = 0; dj < 3; ++dj)
                    s += smem[TB2v + src + di * R3C + dj];
            smem[OUT2 + n] = d * s + b3[8];
        } else {
            const int tb = p ? TB1 : TB0;
            float4 s = {0.f, 0.f, 0.f, 0.f};
            #pragma unroll
            for (int di = 0; di < 3; ++di)
                #pragma unroll
                for (int dj = 0; dj < 3; ++dj)
                    add4(s, *(const float4*)&smem[tb + (src + di * R3C + dj) * 4]);
            const float4 bb = *(const float4*)&b3[4 * p];
            float4 o;
            o.x = d * s.x + bb.x; o.y = d * s.y + bb.y;
            o.z = d * s.z + bb.z; o.w = d * s.w + bb.w;
            *(float4*)&smem[(p ? OUT1 : OUT0) + n * 4] = o;
        }
    }
    __syncthreads();

    // ====== pixel-shuffle write: 36 rows x 96 cols per block, float4 stores ======
    #define ORD(n, c) ((c) < 8 ? smem[((c) < 4 ? OUT0 : OUT1) + (n) * 4 + ((c) & 3)] \
                               : smem[OUT2 + (n)])
    for (int q = tid; q < 36 * 24; q += NT) {      // 864 float4 stores
        int rr = q / 24, cc0 = 4 * (q % 24);
        int ii = rr / 3, si = rr - 3 * ii;
        float4 o;
        { int cc = cc0 + 0, jj = cc / 3, sj = cc - 3 * jj; o.x = ORD(ii * TJ + jj, si * 3 + sj); }
        { int cc = cc0 + 1, jj = cc / 3, sj = cc - 3 * jj; o.y = ORD(ii * TJ + jj, si * 3 + sj); }
        { int cc = cc0 + 2, jj = cc / 3, sj = cc - 3 * jj; o.z = ORD(ii * TJ + jj, si * 3 + sj); }
        { int cc = cc0 + 3, jj = cc / 3, sj = cc - 3 * jj; o.w = ORD(ii * TJ + jj, si * 3 + sj); }
        *(float4*)&out[(size_t)(oi * SS + rr) * (HH * SS) + oj * SS + cc0] = o;
    }
}

extern "C" void kernel_launch(void* const* d_in, const int* in_sizes, int n_in,
                              void* d_out, int out_size, void* d_ws, size_t ws_size,
                              hipStream_t stream) {
    const float* x  = (const float*)d_in[0];
    // d_in[1] = edge_index (int32) — fixed grid; derived analytically.
    const float* W1 = (const float*)d_in[2];
    const float* b1 = (const float*)d_in[3];
    const float* W2 = (const float*)d_in[4];
    const float* b2 = (const float*)d_in[5];
    const float* W3 = (const float*)d_in[6];
    const float* b3 = (const float*)d_in[7];
    float* out = (float*)d_out;

    pack_weights<<<dim3(1), dim3(NT), 0, stream>>>(W2, W3);
    gnn_fused<<<dim3(64 * NBJ), dim3(NT), 0, stream>>>(x, W1, b1, b2, b3, out);
}

// Round 9
// 43.199 us; speedup vs baseline: 26.6533x; 1.1833x over previous
//
#include <hip/hip_runtime.h>

// SatelliteImageGNN: 3-layer GCN on a 768x768 8-neighbor grid + pixel shuffle.
// layer = dinv * boxsum3x3(dinv .* h) @ W + b ; dinv from position (edge_index unused).
// Round-9 (= round-8 + fix): mm2/mm3 on the matrix pipe via v_mfma_f32_16x16x32_f16.
// FIX: h-repack base offset — ACT1 wrote h at halfword row*40 but MISSED the s1p
// region base (2*S1P halfwords), clobbering low LDS and leaving mm3 reading stale s1.
// Also: zero s1p pad rows 476..479 (were uninitialized, read by tile 29's A-frag).

constexpr int HH = 768, SS = 3;
constexpr int TI = 12, TJ = 32;
constexpr int NBJ = 24;                 // 768/TJ
constexpr int NT = 512;

constexpr int G0C = 38;  constexpr int N0  = 684;   // g0: 18x38, origin (-3,-3)
constexpr int S0C = 36;  constexpr int NS0 = 576;   // s0/g1: 16x36, origin (-2,-2)
constexpr int R3C = 34;  constexpr int NS1 = 476;   // h2/t: 14x34, origin (-1,-1)
constexpr int NS1P = 480;                           // padded to 30 row-tiles of 16
constexpr int ON  = 384;                            // 12*32
constexpr int S1STR = 20;                           // u32 stride per s1p/h2p row (16 data + 4 pad)

// ---- LDS float offsets ----
constexpr int G0O = 0;                  // 684 f4 = 2736
constexpr int G1A = 0;                  // 576 x 2 fl (f16x4) = 1152 (over dead G0)
constexpr int G1B = 1152;               // ..2304
constexpr int S1P = 2304;               // 480 x 20 u32 = 9600 -> ..11904 (s1, then h in-place)
constexpr int D3O = S1P + NS1P * S1STR; // 11904 : 480 -> ..12384
constexpr int SMEMF = D3O + NS1P;       // 12384 fl = 49,536 B -> 3 blocks/CU

// overlays (barrier-protected; see phase sequence)
constexpr int TB0 = 0;                  // t cols 0-3 : 480*4 = 1920
constexpr int TB1 = 1920;               // t cols 4-7 : ..3840
constexpr int TB2 = 3840;               // t col 8    : ..4320
constexpr int OUT0 = 4320;              // [384][4] = 1536
constexpr int OUT1 = 5856;              // 1536
constexpr int OUT2 = 7392;              // 384 -> ..7776 (over dead s1p/h rows)

__device__ uint32_t g_wfrag[768];       // [0,512): W2 B-frags (2 col-tiles x 64 lanes x 4 u32)
                                        // [512,768): W3 B-frags (64 lanes x 4 u32, cols>=9 zero)

typedef _Float16 f16x8 __attribute__((ext_vector_type(8)));
typedef float    f32x4 __attribute__((ext_vector_type(4)));
using h2 = decltype(__builtin_amdgcn_cvt_pkrtz(0.f, 0.f));

#define PK(a, b)  __builtin_amdgcn_cvt_pkrtz((a), (b))
#define BC2(u)    __builtin_bit_cast(h2, (u))
#define BCU(x)    __builtin_bit_cast(uint32_t, (x))
#define MFMA16(a, b, c) __builtin_amdgcn_mfma_f32_16x16x32_f16((a), (b), (c), 0, 0, 0)

__device__ __forceinline__ float dinv_of(int gi, int gj) {
    int e = (1 + (gi > 0) + (gi < HH - 1)) * (1 + (gj > 0) + (gj < HH - 1));
    return e == 9 ? 0.33333334f : (e == 6 ? 0.40824829f : 0.5f);
}
__device__ __forceinline__ void add4(float4& a, const float4 v) {
    a.x += v.x; a.y += v.y; a.z += v.z; a.w += v.w;
}
#define FMA4G(acc, s, wp) { const float4 _w = *(const float4*)(wp); \
    acc.x += (s) * _w.x; acc.y += (s) * _w.y; acc.z += (s) * _w.z; acc.w += (s) * _w.w; }

// k-pair order inside each fragment u32: (even chan, odd chan) — identical on A and B sides.
__global__ __launch_bounds__(NT) void pack_weights(const float* __restrict__ W2,
                                                   const float* __restrict__ W3) {
    const int t = threadIdx.x;
    {   // W2 frag: col-tile ct, lane, reg j. col n = ct*16+(lane&15), k0 = 8*(lane>>4)+2j
        int ct = t >> 8, lane = (t >> 2) & 63, j = t & 3;
        int n = ct * 16 + (lane & 15);
        int k0 = 8 * (lane >> 4) + 2 * j;
        g_wfrag[t] = BCU(PK(W2[k0 * 32 + n], W2[(k0 + 1) * 32 + n]));
    }
    if (t < 256) {
        int lane = t >> 2, j = t & 3;
        int n = lane & 15;
        int k0 = 8 * (lane >> 4) + 2 * j;
        float a = 0.f, b = 0.f;
        if (n < 9) { a = W3[k0 * 9 + n]; b = W3[(k0 + 1) * 9 + n]; }
        g_wfrag[512 + t] = BCU(PK(a, b));
    }
}

__global__ __launch_bounds__(NT) void gnn_fused(
    const float* __restrict__ x,
    const float* __restrict__ W1, const float* __restrict__ b1,
    const float* __restrict__ b2, const float* __restrict__ b3,
    float* __restrict__ out)
{
    __shared__ __align__(16) float smem[SMEMF];
    const int tid = threadIdx.x;
    const int bi = blockIdx.x / NBJ;
    const int bj = blockIdx.x % NBJ;
    const int oi = bi * TI, oj = bj * TJ;

    // ================= phase 0: stage g0 = dinv .* x (18x38) + D3 plane =================
    for (int n = tid; n < N0; n += NT) {
        int li = n / G0C, lj = n - li * G0C;
        int gi = oi - 3 + li, gj = oj - 3 + lj;
        float4 v = {0.f, 0.f, 0.f, 0.f};
        if ((unsigned)gi < HH && (unsigned)gj < HH) {
            float d = dinv_of(gi, gj);
            const float* xp = x + 3 * ((size_t)gi * HH + gj);
            v.x = d * xp[0]; v.y = d * xp[1]; v.z = d * xp[2];
        }
        *(float4*)&smem[G0O + n * 4] = v;
    }
    if (tid < NS1P) {     // dinv on the L2 domain; 0 for out-of-grid AND pad nodes 476..479
        float v = 0.f;
        if (tid < NS1) {
            int li = tid / R3C, lj = tid - li * R3C;
            int gi = oi - 1 + li, gj = oj - 1 + lj;
            if ((unsigned)gi < HH && (unsigned)gj < HH) v = dinv_of(gi, gj);
        }
        smem[D3O + tid] = v;
    }
    if (tid < 4 * S1STR)  // zero s1p pad rows 476..479 (read as A-frag rows of tile 29)
        smem[S1P + NS1 * S1STR + tid] = 0.f;
    __syncthreads();

    // ============ phase 1: s0 + d2 into registers (own nodes only) ============
    float4 s0a = {0,0,0,0}, s0b = {0,0,0,0};
    float d2a = 0.f, d2b = 0.f;
    {
        int li = tid / S0C, lj = tid - li * S0C;
        int base = li * G0C + lj;
        #pragma unroll
        for (int di = 0; di < 3; ++di)
            #pragma unroll
            for (int dj = 0; dj < 3; ++dj)
                add4(s0a, *(const float4*)&smem[G0O + (base + di * G0C + dj) * 4]);
        int gi = oi - 2 + li, gj = oj - 2 + lj;
        if ((unsigned)gi < HH && (unsigned)gj < HH) d2a = dinv_of(gi, gj);
    }
    if (tid < NS0 - NT) {
        int n = tid + NT;
        int li = n / S0C, lj = n - li * S0C;
        int base = li * G0C + lj;
        #pragma unroll
        for (int di = 0; di < 3; ++di)
            #pragma unroll
            for (int dj = 0; dj < 3; ++dj)
                add4(s0b, *(const float4*)&smem[G0O + (base + di * G0C + dj) * 4]);
        int gi = oi - 2 + li, gj = oj - 2 + lj;
        if ((unsigned)gi < HH && (unsigned)gj < HH) d2b = dinv_of(gi, gj);
    }
    const int fli = tid / R3C, flj = tid - fli * R3C;
    const int fbase = fli * S0C + flj;
    __syncthreads();   // g0 dead; G1A/G1B may overlay

    // mm1 quad q from register s0 -> packed f16 (1 b64 write per node)
    #define MM1Q(q, BUF) { \
        { float4 a = {0,0,0,0}; \
          FMA4G(a, s0a.x, W1 + 4 * (q)) FMA4G(a, s0a.y, W1 + 32 + 4 * (q)) FMA4G(a, s0a.z, W1 + 64 + 4 * (q)) \
          const float4 bb = *(const float4*)&b1[4 * (q)]; \
          float gx = d2a * fmaxf(d2a * a.x + bb.x, 0.f); \
          float gy = d2a * fmaxf(d2a * a.y + bb.y, 0.f); \
          float gz = d2a * fmaxf(d2a * a.z + bb.z, 0.f); \
          float gw = d2a * fmaxf(d2a * a.w + bb.w, 0.f); \
          uint2 u; u.x = BCU(PK(gx, gy)); u.y = BCU(PK(gz, gw)); \
          *(uint2*)&smem[(BUF) + tid * 2] = u; } \
        if (tid < NS0 - NT) { float4 a = {0,0,0,0}; \
          FMA4G(a, s0b.x, W1 + 4 * (q)) FMA4G(a, s0b.y, W1 + 32 + 4 * (q)) FMA4G(a, s0b.z, W1 + 64 + 4 * (q)) \
          const float4 bb = *(const float4*)&b1[4 * (q)]; \
          float gx = d2b * fmaxf(d2b * a.x + bb.x, 0.f); \
          float gy = d2b * fmaxf(d2b * a.y + bb.y, 0.f); \
          float gz = d2b * fmaxf(d2b * a.z + bb.z, 0.f); \
          float gw = d2b * fmaxf(d2b * a.w + bb.w, 0.f); \
          uint2 u; u.x = BCU(PK(gx, gy)); u.y = BCU(PK(gz, gw)); \
          *(uint2*)&smem[(BUF) + (tid + NT) * 2] = u; } \
    }

    // bs2: 9-tap f16 boxsum of quad q -> s1p[node][u32 2q..2q+1]
    #define BS2Q(q, BUF) \
        if (tid < NS1) { \
            const int _tb = (BUF) + fbase * 2; \
            const uint2 u00 = *(const uint2*)&smem[_tb + 0]; \
            const uint2 u01 = *(const uint2*)&smem[_tb + 2]; \
            const uint2 u02 = *(const uint2*)&smem[_tb + 4]; \
            const uint2 u10 = *(const uint2*)&smem[_tb + 2 * S0C + 0]; \
            const uint2 u11 = *(const uint2*)&smem[_tb + 2 * S0C + 2]; \
            const uint2 u12 = *(const uint2*)&smem[_tb + 2 * S0C + 4]; \
            const uint2 u20 = *(const uint2*)&smem[_tb + 4 * S0C + 0]; \
            const uint2 u21 = *(const uint2*)&smem[_tb + 4 * S0C + 2]; \
            const uint2 u22 = *(const uint2*)&smem[_tb + 4 * S0C + 4]; \
            h2 rl0 = (BC2(u00.x) + BC2(u01.x)) + BC2(u02.x); \
            h2 rl1 = (BC2(u10.x) + BC2(u11.x)) + BC2(u12.x); \
            h2 rl2 = (BC2(u20.x) + BC2(u21.x)) + BC2(u22.x); \
            h2 sl  = (rl0 + rl1) + rl2; \
            h2 rh0 = (BC2(u00.y) + BC2(u01.y)) + BC2(u02.y); \
            h2 rh1 = (BC2(u10.y) + BC2(u11.y)) + BC2(u12.y); \
            h2 rh2 = (BC2(u20.y) + BC2(u21.y)) + BC2(u22.y); \
            h2 sh  = (rh0 + rh1) + rh2; \
            uint2 uo; uo.x = BCU(sl); uo.y = BCU(sh); \
            *(uint2*)&smem[S1P + tid * S1STR + 2 * (q)] = uo; \
        }

    // ---- ping-pong over 8 channel-quads ----
    MM1Q(0, G1A) __syncthreads();
    BS2Q(0, G1A) MM1Q(1, G1B) __syncthreads();
    BS2Q(1, G1B) MM1Q(2, G1A) __syncthreads();
    BS2Q(2, G1A) MM1Q(3, G1B) __syncthreads();
    BS2Q(3, G1B) MM1Q(4, G1A) __syncthreads();
    BS2Q(4, G1A) MM1Q(5, G1B) __syncthreads();
    BS2Q(5, G1B) MM1Q(6, G1A) __syncthreads();
    BS2Q(6, G1A) MM1Q(7, G1B) __syncthreads();
    BS2Q(7, G1B)
    __syncthreads();   // s1p complete

    // ================= MFMA section =================
    const int lane = tid & 63, wid = tid >> 6;
    const int lr = lane & 15, lg = lane >> 4;
    const uint4* wf = (const uint4*)g_wfrag;
    const f16x8 bw20 = __builtin_bit_cast(f16x8, wf[lane]);
    const f16x8 bw21 = __builtin_bit_cast(f16x8, wf[64 + lane]);
    const f16x8 bw3  = __builtin_bit_cast(f16x8, wf[128 + lane]);
    const float b2c0 = b2[lr], b2c1 = b2[16 + lr];
    _Float16* hp = (_Float16*)smem;

    // mm2 + act + repack h (f16) IN-PLACE over s1p — wave-local rows, no barrier needed.
    // h halfword index = 2*S1P + row*(2*S1STR) + col  (col 0..31).  [FIX: +2*S1P base]
    #define ACT1(dv, c0r, c1r, rr) { \
        float h0 = (dv) * fmaxf((dv) * (c0r) + b2c0, 0.f); \
        float h1 = (dv) * fmaxf((dv) * (c1r) + b2c1, 0.f); \
        const int hb = 2 * S1P + (nb + (rr)) * (2 * S1STR); \
        hp[hb + lr] = (_Float16)h0; \
        hp[hb + 16 + lr] = (_Float16)h1; }

    #define MM2TILE(rt) { \
        f16x8 aa = __builtin_bit_cast(f16x8, *(const uint4*)&smem[S1P + ((rt) * 16 + lr) * S1STR + lg * 4]); \
        f32x4 c0 = {0.f, 0.f, 0.f, 0.f}, c1 = {0.f, 0.f, 0.f, 0.f}; \
        c0 = MFMA16(aa, bw20, c0); \
        c1 = MFMA16(aa, bw21, c1); \
        const int nb = (rt) * 16 + lg * 4; \
        const float4 dd = *(const float4*)&smem[D3O + nb]; \
        ACT1(dd.x, c0[0], c1[0], 0) \
        ACT1(dd.y, c0[1], c1[1], 1) \
        ACT1(dd.z, c0[2], c1[2], 2) \
        ACT1(dd.w, c0[3], c1[3], 3) }

    MM2TILE(wid)
    MM2TILE(wid + 8)
    MM2TILE(wid + 16)
    if (wid < 6) { MM2TILE(wid + 24) }
    __syncthreads();   // all h writes done

    // load mm3 A-frags to registers BEFORE t overlays h rows 0..100
    #define LDA3(rt) __builtin_bit_cast(f16x8, *(const uint4*)&smem[S1P + ((rt) * 16 + lr) * S1STR + lg * 4])
    f16x8 a30 = LDA3(wid);
    f16x8 a31 = LDA3(wid + 8);
    f16x8 a32 = LDA3(wid + 16);
    f16x8 a33 = a30;
    if (wid < 6) a33 = LDA3(wid + 24);
    __syncthreads();   // every wave's A-frag loads complete before TB overlay

    #define MM3TILE(rt, af) { \
        f32x4 tt = {0.f, 0.f, 0.f, 0.f}; \
        tt = MFMA16((af), bw3, tt); \
        const int nb = (rt) * 16 + lg * 4; \
        if (lr < 4) { \
            smem[TB0 + (nb + 0) * 4 + lr] = tt[0]; \
            smem[TB0 + (nb + 1) * 4 + lr] = tt[1]; \
            smem[TB0 + (nb + 2) * 4 + lr] = tt[2]; \
            smem[TB0 + (nb + 3) * 4 + lr] = tt[3]; \
        } else if (lr < 8) { \
            smem[TB1 + (nb + 0) * 4 + lr - 4] = tt[0]; \
            smem[TB1 + (nb + 1) * 4 + lr - 4] = tt[1]; \
            smem[TB1 + (nb + 2) * 4 + lr - 4] = tt[2]; \
            smem[TB1 + (nb + 3) * 4 + lr - 4] = tt[3]; \
        } else if (lr == 8) { \
            smem[TB2 + nb + 0] = tt[0]; \
            smem[TB2 + nb + 1] = tt[1]; \
            smem[TB2 + nb + 2] = tt[2]; \
            smem[TB2 + nb + 3] = tt[3]; } }

    MM3TILE(wid, a30)
    MM3TILE(wid + 8, a31)
    MM3TILE(wid + 16, a32)
    if (wid < 6) { MM3TILE(wid + 24, a33) }
    __syncthreads();

    // ====== bs3 + epilogue: out = dinv*boxsum(t) + b3 -> planar outbuf ======
    for (int item = tid; item < 3 * ON; item += NT) {
        int p = item / ON, n = item - p * ON;
        int li = n >> 5, lj = n & 31;
        int src = li * R3C + lj;
        float d = dinv_of(oi + li, oj + lj);
        if (p == 2) {
            float s = 0.f;
            #pragma unroll
            for (int di = 0; di < 3; ++di)
                #pragma unroll
                for (int dj = 0; dj < 3; ++dj)
                    s += smem[TB2 + src + di * R3C + dj];
            smem[OUT2 + n] = d * s + b3[8];
        } else {
            const int tb = p ? TB1 : TB0;
            float4 s = {0.f, 0.f, 0.f, 0.f};
            #pragma unroll
            for (int di = 0; di < 3; ++di)
                #pragma unroll
                for (int dj = 0; dj < 3; ++dj)
                    add4(s, *(const float4*)&smem[tb + (src + di * R3C + dj) * 4]);
            const float4 bb = *(const float4*)&b3[4 * p];
            float4 o;
            o.x = d * s.x + bb.x; o.y = d * s.y + bb.y;
            o.z = d * s.z + bb.z; o.w = d * s.w + bb.w;
            *(float4*)&smem[(p ? OUT1 : OUT0) + n * 4] = o;
        }
    }
    __syncthreads();

    // ====== pixel-shuffle write: 36 rows x 96 cols per block, float4 stores ======
    #define ORD(n, c) ((c) < 8 ? smem[((c) < 4 ? OUT0 : OUT1) + (n) * 4 + ((c) & 3)] \
                               : smem[OUT2 + (n)])
    for (int q = tid; q < 36 * 24; q += NT) {      // 864 float4 stores
        int rr = q / 24, cc0 = 4 * (q % 24);
        int ii = rr / 3, si = rr - 3 * ii;
        float4 o;
        { int cc = cc0 + 0, jj = cc / 3, sj = cc - 3 * jj; o.x = ORD(ii * TJ + jj, si * 3 + sj); }
        { int cc = cc0 + 1, jj = cc / 3, sj = cc - 3 * jj; o.y = ORD(ii * TJ + jj, si * 3 + sj); }
        { int cc = cc0 + 2, jj = cc / 3, sj = cc - 3 * jj; o.z = ORD(ii * TJ + jj, si * 3 + sj); }
        { int cc = cc0 + 3, jj = cc / 3, sj = cc - 3 * jj; o.w = ORD(ii * TJ + jj, si * 3 + sj); }
        *(float4*)&out[(size_t)(oi * SS + rr) * (HH * SS) + oj * SS + cc0] = o;
    }
}

extern "C" void kernel_launch(void* const* d_in, const int* in_sizes, int n_in,
                              void* d_out, int out_size, void* d_ws, size_t ws_size,
                              hipStream_t stream) {
    const float* x  = (const float*)d_in[0];
    // d_in[1] = edge_index (int32) — fixed grid; derived analytically.
    const float* W1 = (const float*)d_in[2];
    const float* b1 = (const float*)d_in[3];
    const float* W2 = (const float*)d_in[4];
    const float* b2 = (const float*)d_in[5];
    const float* W3 = (const float*)d_in[6];
    const float* b3 = (const float*)d_in[7];
    float* out = (float*)d_out;

    pack_weights<<<dim3(1), dim3(NT), 0, stream>>>(W2, W3);
    gnn_fused<<<dim3(64 * NBJ), dim3(NT), 0, stream>>>(x, W1, b1, b2, b3, out);
}

// Round 10
// 41.413 us; speedup vs baseline: 27.8032x; 1.0431x over previous
//
#include <hip/hip_runtime.h>

// SatelliteImageGNN: 3-layer GCN on a 768x768 8-neighbor grid + pixel shuffle.
// layer = dinv * boxsum3x3(dinv .* h) @ W + b ; dinv from position (edge_index unused).
// Round-10: 4 blocks/CU (32 waves = occupancy cap). LDS 49.5 -> 39.9 KB via
// s1p stride 20->16 u32 with XOR swizzle (col ^= ((row>>1)&3)<<2) and D3 plane
// dropped (dinv recomputed via magic-div by 34). pack_weights prekernel removed:
// per-lane B-fragments built straight from global W2/W3 (L2-hot), hidden under
// the last ping-pong phase. __launch_bounds__(512,8) caps VGPR at 64.

constexpr int HH = 768, SS = 3;
constexpr int TI = 12, TJ = 32;
constexpr int NBJ = 24;                 // 768/TJ
constexpr int NT = 512;

constexpr int G0C = 38;  constexpr int N0  = 684;   // g0: 18x38, origin (-3,-3)
constexpr int S0C = 36;  constexpr int NS0 = 576;   // s0/g1: 16x36, origin (-2,-2)
constexpr int R3C = 34;  constexpr int NS1 = 476;   // h2/t: 14x34, origin (-1,-1)
constexpr int NS1P = 480;                           // 30 row-tiles of 16
constexpr int ON  = 384;                            // 12*32

// ---- LDS float offsets ----
constexpr int G0O = 0;                  // 684 f4 = 2736 (dead after phase 1)
constexpr int G1A = 0;                  // 576 x 2 fl (f16x4) = 1152 (over dead G0)
constexpr int G1B = 1152;               // ..2304
constexpr int S1P = 2304;               // 480 rows x 16 u32 (XOR-swizzled) -> ..9984
constexpr int SMEMF = S1P + NS1P * 16;  // 9984 fl = 39,936 B -> 4 blocks/CU

// overlays (barrier-protected):
constexpr int TB0 = 0;                  // t cols 0-3 : 480*4 = 1920
constexpr int TB1 = 1920;               // t cols 4-7 : ..3840
constexpr int TB2 = 3840;               // t col 8    : ..4320
constexpr int OUT0 = 4320;              // [384][4] = 1536
constexpr int OUT1 = 5856;              // 1536
constexpr int OUT2 = 7392;              // 384 -> ..7776 (over dead s1p/h rows)

// XOR swizzle on the 16-u32 s1p row: group-preserving, involutive
#define SWZ(row) ((((row) >> 1) & 3) << 2)

typedef _Float16 f16x8 __attribute__((ext_vector_type(8)));
typedef float    f32x4 __attribute__((ext_vector_type(4)));
using h2 = decltype(__builtin_amdgcn_cvt_pkrtz(0.f, 0.f));

#define PK(a, b)  __builtin_amdgcn_cvt_pkrtz((a), (b))
#define BC2(u)    __builtin_bit_cast(h2, (u))
#define BCU(x)    __builtin_bit_cast(uint32_t, (x))
#define MFMA16(a, b, c) __builtin_amdgcn_mfma_f32_16x16x32_f16((a), (b), (c), 0, 0, 0)

__device__ __forceinline__ float dinv_of(int gi, int gj) {
    int e = (1 + (gi > 0) + (gi < HH - 1)) * (1 + (gj > 0) + (gj < HH - 1));
    return e == 9 ? 0.33333334f : (e == 6 ? 0.40824829f : 0.5f);
}
// dinv for L2-domain node nb (row-major, stride 34); exact for nb <= 512
__device__ __forceinline__ float dinv_node(int nb, int oi, int oj) {
    int li = (nb * 241) >> 13;          // nb / 34
    int lj = nb - li * 34;
    int gi = oi - 1 + li, gj = oj - 1 + lj;
    if ((unsigned)gi >= HH || (unsigned)gj >= HH) return 0.f;
    return dinv_of(gi, gj);
}
__device__ __forceinline__ void add4(float4& a, const float4 v) {
    a.x += v.x; a.y += v.y; a.z += v.z; a.w += v.w;
}
#define FMA4G(acc, s, wp) { const float4 _w = *(const float4*)(wp); \
    acc.x += (s) * _w.x; acc.y += (s) * _w.y; acc.z += (s) * _w.z; acc.w += (s) * _w.w; }

__global__ __launch_bounds__(NT, 8) void gnn_fused(
    const float* __restrict__ x,
    const float* __restrict__ W1, const float* __restrict__ b1,
    const float* __restrict__ W2, const float* __restrict__ b2,
    const float* __restrict__ W3, const float* __restrict__ b3,
    float* __restrict__ out)
{
    __shared__ __align__(16) float smem[SMEMF];
    const int tid = threadIdx.x;
    const int lane = tid & 63, wid = tid >> 6;
    const int lr = lane & 15, lg = lane >> 4;
    const int bi = blockIdx.x / NBJ;
    const int bj = blockIdx.x % NBJ;
    const int oi = bi * TI, oj = bj * TJ;

    // ================= phase 0: stage g0 = dinv .* x (18x38); zero s1p pad rows =================
    for (int n = tid; n < N0; n += NT) {
        int li = n / G0C, lj = n - li * G0C;
        int gi = oi - 3 + li, gj = oj - 3 + lj;
        float4 v = {0.f, 0.f, 0.f, 0.f};
        if ((unsigned)gi < HH && (unsigned)gj < HH) {
            float d = dinv_of(gi, gj);
            const float* xp = x + 3 * ((size_t)gi * HH + gj);
            v.x = d * xp[0]; v.y = d * xp[1]; v.z = d * xp[2];
        }
        *(float4*)&smem[G0O + n * 4] = v;
    }
    if (tid < 64)   // rows 476..479 (tile 29's pad) must be zero for mm2 A-frags
        smem[S1P + NS1 * 16 + tid] = 0.f;
    __syncthreads();

    // ============ phase 1: s0 + d2 into registers (own nodes only) ============
    float4 s0a = {0,0,0,0}, s0b = {0,0,0,0};
    float d2a = 0.f, d2b = 0.f;
    {
        int li = tid / S0C, lj = tid - li * S0C;
        int base = li * G0C + lj;
        #pragma unroll
        for (int di = 0; di < 3; ++di)
            #pragma unroll
            for (int dj = 0; dj < 3; ++dj)
                add4(s0a, *(const float4*)&smem[G0O + (base + di * G0C + dj) * 4]);
        int gi = oi - 2 + li, gj = oj - 2 + lj;
        if ((unsigned)gi < HH && (unsigned)gj < HH) d2a = dinv_of(gi, gj);
    }
    if (tid < NS0 - NT) {
        int n = tid + NT;
        int li = n / S0C, lj = n - li * S0C;
        int base = li * G0C + lj;
        #pragma unroll
        for (int di = 0; di < 3; ++di)
            #pragma unroll
            for (int dj = 0; dj < 3; ++dj)
                add4(s0b, *(const float4*)&smem[G0O + (base + di * G0C + dj) * 4]);
        int gi = oi - 2 + li, gj = oj - 2 + lj;
        if ((unsigned)gi < HH && (unsigned)gj < HH) d2b = dinv_of(gi, gj);
    }
    const int fli = tid / R3C, flj = tid - fli * R3C;
    const int fbase = fli * S0C + flj;
    __syncthreads();   // g0 dead; G1A/G1B may overlay

    // mm1 quad q from register s0 -> packed f16 (1 b64 write per node)
    #define MM1Q(q, BUF) { \
        { float4 a = {0,0,0,0}; \
          FMA4G(a, s0a.x, W1 + 4 * (q)) FMA4G(a, s0a.y, W1 + 32 + 4 * (q)) FMA4G(a, s0a.z, W1 + 64 + 4 * (q)) \
          const float4 bb = *(const float4*)&b1[4 * (q)]; \
          float gx = d2a * fmaxf(d2a * a.x + bb.x, 0.f); \
          float gy = d2a * fmaxf(d2a * a.y + bb.y, 0.f); \
          float gz = d2a * fmaxf(d2a * a.z + bb.z, 0.f); \
          float gw = d2a * fmaxf(d2a * a.w + bb.w, 0.f); \
          uint2 u; u.x = BCU(PK(gx, gy)); u.y = BCU(PK(gz, gw)); \
          *(uint2*)&smem[(BUF) + tid * 2] = u; } \
        if (tid < NS0 - NT) { float4 a = {0,0,0,0}; \
          FMA4G(a, s0b.x, W1 + 4 * (q)) FMA4G(a, s0b.y, W1 + 32 + 4 * (q)) FMA4G(a, s0b.z, W1 + 64 + 4 * (q)) \
          const float4 bb = *(const float4*)&b1[4 * (q)]; \
          float gx = d2b * fmaxf(d2b * a.x + bb.x, 0.f); \
          float gy = d2b * fmaxf(d2b * a.y + bb.y, 0.f); \
          float gz = d2b * fmaxf(d2b * a.z + bb.z, 0.f); \
          float gw = d2b * fmaxf(d2b * a.w + bb.w, 0.f); \
          uint2 u; u.x = BCU(PK(gx, gy)); u.y = BCU(PK(gz, gw)); \
          *(uint2*)&smem[(BUF) + (tid + NT) * 2] = u; } \
    }

    // bs2: 9-tap f16 boxsum of quad q -> s1p[row tid][u32 (2q,2q+1) ^ swz]
    #define BS2Q(q, BUF) \
        if (tid < NS1) { \
            const int _tb = (BUF) + fbase * 2; \
            const uint2 u00 = *(const uint2*)&smem[_tb + 0]; \
            const uint2 u01 = *(const uint2*)&smem[_tb + 2]; \
            const uint2 u02 = *(const uint2*)&smem[_tb + 4]; \
            const uint2 u10 = *(const uint2*)&smem[_tb + 2 * S0C + 0]; \
            const uint2 u11 = *(const uint2*)&smem[_tb + 2 * S0C + 2]; \
            const uint2 u12 = *(const uint2*)&smem[_tb + 2 * S0C + 4]; \
            const uint2 u20 = *(const uint2*)&smem[_tb + 4 * S0C + 0]; \
            const uint2 u21 = *(const uint2*)&smem[_tb + 4 * S0C + 2]; \
            const uint2 u22 = *(const uint2*)&smem[_tb + 4 * S0C + 4]; \
            h2 rl0 = (BC2(u00.x) + BC2(u01.x)) + BC2(u02.x); \
            h2 rl1 = (BC2(u10.x) + BC2(u11.x)) + BC2(u12.x); \
            h2 rl2 = (BC2(u20.x) + BC2(u21.x)) + BC2(u22.x); \
            h2 sl  = (rl0 + rl1) + rl2; \
            h2 rh0 = (BC2(u00.y) + BC2(u01.y)) + BC2(u02.y); \
            h2 rh1 = (BC2(u10.y) + BC2(u11.y)) + BC2(u12.y); \
            h2 rh2 = (BC2(u20.y) + BC2(u21.y)) + BC2(u22.y); \
            h2 sh  = (rh0 + rh1) + rh2; \
            uint2 uo; uo.x = BCU(sl); uo.y = BCU(sh); \
            *(uint2*)&smem[S1P + tid * 16 + (2 * (q) ^ SWZ(tid))] = uo; \
        }

    // ---- ping-pong over 8 channel-quads ----
    MM1Q(0, G1A) __syncthreads();
    BS2Q(0, G1A) MM1Q(1, G1B) __syncthreads();
    BS2Q(1, G1B) MM1Q(2, G1A) __syncthreads();
    BS2Q(2, G1A) MM1Q(3, G1B) __syncthreads();
    BS2Q(3, G1B) MM1Q(4, G1A) __syncthreads();
    BS2Q(4, G1A) MM1Q(5, G1B) __syncthreads();
    BS2Q(5, G1B) MM1Q(6, G1A) __syncthreads();
    BS2Q(6, G1A) MM1Q(7, G1B) __syncthreads();
    BS2Q(7, G1B)

    // per-lane MFMA B-fragments straight from global (L2-hot; replaces prekernel).
    // k-pair order (even,odd) matches the A-side packing; mapping identical to the
    // verified round-9 pack_weights.
    uint4 uw20, uw21, uw3;
    {
        const int k0 = 8 * lg;
        uw20.x = BCU(PK(W2[(k0+0)*32 + lr],      W2[(k0+1)*32 + lr]));
        uw20.y = BCU(PK(W2[(k0+2)*32 + lr],      W2[(k0+3)*32 + lr]));
        uw20.z = BCU(PK(W2[(k0+4)*32 + lr],      W2[(k0+5)*32 + lr]));
        uw20.w = BCU(PK(W2[(k0+6)*32 + lr],      W2[(k0+7)*32 + lr]));
        uw21.x = BCU(PK(W2[(k0+0)*32 + 16 + lr], W2[(k0+1)*32 + 16 + lr]));
        uw21.y = BCU(PK(W2[(k0+2)*32 + 16 + lr], W2[(k0+3)*32 + 16 + lr]));
        uw21.z = BCU(PK(W2[(k0+4)*32 + 16 + lr], W2[(k0+5)*32 + 16 + lr]));
        uw21.w = BCU(PK(W2[(k0+6)*32 + 16 + lr], W2[(k0+7)*32 + 16 + lr]));
        float a0w=0.f,b0w=0.f,a1w=0.f,b1w=0.f,a2w=0.f,b2w=0.f,a3w=0.f,b3w=0.f;
        if (lr < 9) {
            a0w = W3[(k0+0)*9 + lr]; b0w = W3[(k0+1)*9 + lr];
            a1w = W3[(k0+2)*9 + lr]; b1w = W3[(k0+3)*9 + lr];
            a2w = W3[(k0+4)*9 + lr]; b2w = W3[(k0+5)*9 + lr];
            a3w = W3[(k0+6)*9 + lr]; b3w = W3[(k0+7)*9 + lr];
        }
        uw3.x = BCU(PK(a0w, b0w)); uw3.y = BCU(PK(a1w, b1w));
        uw3.z = BCU(PK(a2w, b2w)); uw3.w = BCU(PK(a3w, b3w));
    }
    const float b2c0 = b2[lr], b2c1 = b2[16 + lr];
    __syncthreads();   // s1p complete

    // ================= MFMA section =================
    const f16x8 bw20 = __builtin_bit_cast(f16x8, uw20);
    const f16x8 bw21 = __builtin_bit_cast(f16x8, uw21);
    const f16x8 bw3  = __builtin_bit_cast(f16x8, uw3);
    _Float16* hp = (_Float16*)smem;

    // mm2 + act + repack h (f16) IN-PLACE over s1p — wave-local tiles, no barrier needed.
    #define ACT1(dv, c0r, c1r, rr) { \
        const float dd_ = (dv); \
        float h0 = dd_ * fmaxf(dd_ * (c0r) + b2c0, 0.f); \
        float h1 = dd_ * fmaxf(dd_ * (c1r) + b2c1, 0.f); \
        const int row_ = nb + (rr); \
        const int sz_ = SWZ(row_); \
        hp[2 * (S1P + row_ * 16 + ((lr >> 1) ^ sz_)) + (lr & 1)] = (_Float16)h0; \
        hp[2 * (S1P + row_ * 16 + ((8 + (lr >> 1)) ^ sz_)) + (lr & 1)] = (_Float16)h1; }

    #define AFRAG(rt) __builtin_bit_cast(f16x8, \
        *(const uint4*)&smem[S1P + ((rt) * 16 + lr) * 16 + (4 * lg ^ SWZ((rt) * 16 + lr))])

    #define MM2TILE(rt) { \
        f16x8 aa = AFRAG(rt); \
        f32x4 c0 = {0.f, 0.f, 0.f, 0.f}, c1 = {0.f, 0.f, 0.f, 0.f}; \
        c0 = MFMA16(aa, bw20, c0); \
        c1 = MFMA16(aa, bw21, c1); \
        const int nb = (rt) * 16 + lg * 4; \
        ACT1(dinv_node(nb + 0, oi, oj), c0[0], c1[0], 0) \
        ACT1(dinv_node(nb + 1, oi, oj), c0[1], c1[1], 1) \
        ACT1(dinv_node(nb + 2, oi, oj), c0[2], c1[2], 2) \
        ACT1(dinv_node(nb + 3, oi, oj), c0[3], c1[3], 3) }

    MM2TILE(wid)
    MM2TILE(wid + 8)
    MM2TILE(wid + 16)
    if (wid < 6) { MM2TILE(wid + 24) }
    __syncthreads();   // all h writes done

    // load mm3 A-frags to registers BEFORE t overlays h rows 0..127
    f16x8 a30 = AFRAG(wid);
    f16x8 a31 = AFRAG(wid + 8);
    f16x8 a32 = AFRAG(wid + 16);
    f16x8 a33 = a30;
    if (wid < 6) a33 = AFRAG(wid + 24);
    __syncthreads();   // every wave's A-frag loads complete before TB overlay

    #define MM3TILE(rt, af) { \
        f32x4 tt = {0.f, 0.f, 0.f, 0.f}; \
        tt = MFMA16((af), bw3, tt); \
        const int nb = (rt) * 16 + lg * 4; \
        if (lr < 4) { \
            smem[TB0 + (nb + 0) * 4 + lr] = tt[0]; \
            smem[TB0 + (nb + 1) * 4 + lr] = tt[1]; \
            smem[TB0 + (nb + 2) * 4 + lr] = tt[2]; \
            smem[TB0 + (nb + 3) * 4 + lr] = tt[3]; \
        } else if (lr < 8) { \
            smem[TB1 + (nb + 0) * 4 + lr - 4] = tt[0]; \
            smem[TB1 + (nb + 1) * 4 + lr - 4] = tt[1]; \
            smem[TB1 + (nb + 2) * 4 + lr - 4] = tt[2]; \
            smem[TB1 + (nb + 3) * 4 + lr - 4] = tt[3]; \
        } else if (lr == 8) { \
            smem[TB2 + nb + 0] = tt[0]; \
            smem[TB2 + nb + 1] = tt[1]; \
            smem[TB2 + nb + 2] = tt[2]; \
            smem[TB2 + nb + 3] = tt[3]; } }

    MM3TILE(wid, a30)
    MM3TILE(wid + 8, a31)
    MM3TILE(wid + 16, a32)
    if (wid < 6) { MM3TILE(wid + 24, a33) }
    __syncthreads();

    // ====== bs3 + epilogue: out = dinv*boxsum(t) + b3 -> planar outbuf ======
    for (int item = tid; item < 3 * ON; item += NT) {
        int p = item / ON, n = item - p * ON;
        int li = n >> 5, lj = n & 31;
        int src = li * R3C + lj;
        float d = dinv_of(oi + li, oj + lj);
        if (p == 2) {
            float s = 0.f;
            #pragma unroll
            for (int di = 0; di < 3; ++di)
                #pragma unroll
                for (int dj = 0; dj < 3; ++dj)
                    s += smem[TB2 + src + di * R3C + dj];
            smem[OUT2 + n] = d * s + b3[8];
        } else {
            const int tb = p ? TB1 : TB0;
            float4 s = {0.f, 0.f, 0.f, 0.f};
            #pragma unroll
            for (int di = 0; di < 3; ++di)
                #pragma unroll
                for (int dj = 0; dj < 3; ++dj)
                    add4(s, *(const float4*)&smem[tb + (src + di * R3C + dj) * 4]);
            const float4 bb = *(const float4*)&b3[4 * p];
            float4 o;
            o.x = d * s.x + bb.x; o.y = d * s.y + bb.y;
            o.z = d * s.z + bb.z; o.w = d * s.w + bb.w;
            *(float4*)&smem[(p ? OUT1 : OUT0) + n * 4] = o;
        }
    }
    __syncthreads();

    // ====== pixel-shuffle write: 36 rows x 96 cols per block, float4 stores ======
    #define ORD(n, c) ((c) < 8 ? smem[((c) < 4 ? OUT0 : OUT1) + (n) * 4 + ((c) & 3)] \
                               : smem[OUT2 + (n)])
    for (int q = tid; q < 36 * 24; q += NT) {      // 864 float4 stores
        int rr = q / 24, cc0 = 4 * (q % 24);
        int ii = rr / 3, si = rr - 3 * ii;
        float4 o;
        { int cc = cc0 + 0, jj = cc / 3, sj = cc - 3 * jj; o.x = ORD(ii * TJ + jj, si * 3 + sj); }
        { int cc = cc0 + 1, jj = cc / 3, sj = cc - 3 * jj; o.y = ORD(ii * TJ + jj, si * 3 + sj); }
        { int cc = cc0 + 2, jj = cc / 3, sj = cc - 3 * jj; o.z = ORD(ii * TJ + jj, si * 3 + sj); }
        { int cc = cc0 + 3, jj = cc / 3, sj = cc - 3 * jj; o.w = ORD(ii * TJ + jj, si * 3 + sj); }
        *(float4*)&out[(size_t)(oi * SS + rr) * (HH * SS) + oj * SS + cc0] = o;
    }
}

extern "C" void kernel_launch(void* const* d_in, const int* in_sizes, int n_in,
                              void* d_out, int out_size, void* d_ws, size_t ws_size,
                              hipStream_t stream) {
    const float* x  = (const float*)d_in[0];
    // d_in[1] = edge_index (int32) — fixed grid; derived analytically.
    const float* W1 = (const float*)d_in[2];
    const float* b1 = (const float*)d_in[3];
    const float* W2 = (const float*)d_in[4];
    const float* b2 = (const float*)d_in[5];
    const float* W3 = (const float*)d_in[6];
    const float* b3 = (const float*)d_in[7];
    float* out = (float*)d_out;

    gnn_fused<<<dim3(64 * NBJ), dim3(NT), 0, stream>>>(x, W1, b1, W2, b2, W3, b3, out);
}

// Round 11
// 40.249 us; speedup vs baseline: 28.6068x; 1.0289x over previous
//
#include <hip/hip_runtime.h>

// SatelliteImageGNN: 3-layer GCN on a 768x768 8-neighbor grid + pixel shuffle.
// layer = dinv * boxsum3x3(dinv .* h) @ W + b ; dinv from position (edge_index unused).
// Round-11: tile 12x24 -> grid 64x32 = 2048 blocks = EXACTLY 2.0 rounds at
// 4 blocks/CU (round-10's 1536 was 1.5 rounds: half the machine idle 25% of the
// time). Single-node mm1 (448<512), 23 MFMA row-tiles (3/wave), D3 plane restored
// (LDS 33.7 KB << 40,960 B bound). s1p XOR-swizzle + in-place h repack carried over.

constexpr int HH = 768, SS = 3;
constexpr int TI = 12, TJ = 24;
constexpr int NBJ = 32;                 // 768/TJ
constexpr int NT = 512;

constexpr int G0C = 30;  constexpr int N0  = 540;   // g0: 18x30, origin (-3,-3)
constexpr int S0C = 28;  constexpr int NS0 = 448;   // s0/g1: 16x28, origin (-2,-2)
constexpr int R3C = 26;  constexpr int NS1 = 364;   // h2/t: 14x26, origin (-1,-1)
constexpr int NS1P = 368;                           // 23 row-tiles of 16
constexpr int ON  = 288;                            // 12*24

// ---- LDS float offsets ----
constexpr int G0O = 0;                  // 540 f4 = 2160 (dead after phase 1)
constexpr int G1A = 0;                  // 448 x 2 fl (f16x4) = 896 (over dead G0)
constexpr int G1B = 896;                // ..1792
constexpr int S1P = 2176;               // 368 rows x 16 u32 (XOR-swizzled) -> ..8064
constexpr int D3O = 8064;               // 368 -> ..8432
constexpr int SMEMF = 8432;             // 33,728 B -> 4 blocks/CU

// overlays (barrier-protected):
constexpr int TB0 = 0;                  // t cols 0-3 : 368*4 = 1472
constexpr int TB1 = 1472;               // t cols 4-7 : ..2944
constexpr int TB2 = 2944;               // t col 8    : ..3312
constexpr int OUT0 = 3328;              // [288][4] = 1152 -> ..4480
constexpr int OUT1 = 4480;              // ..5632
constexpr int OUT2 = 5632;              // ..5920 (all over dead s1p/h rows)

// XOR swizzle on the 16-u32 s1p row: group-preserving, involutive
#define SWZ(row) ((((row) >> 1) & 3) << 2)

typedef _Float16 f16x8 __attribute__((ext_vector_type(8)));
typedef float    f32x4 __attribute__((ext_vector_type(4)));
using h2 = decltype(__builtin_amdgcn_cvt_pkrtz(0.f, 0.f));

#define PK(a, b)  __builtin_amdgcn_cvt_pkrtz((a), (b))
#define BC2(u)    __builtin_bit_cast(h2, (u))
#define BCU(x)    __builtin_bit_cast(uint32_t, (x))
#define MFMA16(a, b, c) __builtin_amdgcn_mfma_f32_16x16x32_f16((a), (b), (c), 0, 0, 0)

__device__ __forceinline__ float dinv_of(int gi, int gj) {
    int e = (1 + (gi > 0) + (gi < HH - 1)) * (1 + (gj > 0) + (gj < HH - 1));
    return e == 9 ? 0.33333334f : (e == 6 ? 0.40824829f : 0.5f);
}
__device__ __forceinline__ void add4(float4& a, const float4 v) {
    a.x += v.x; a.y += v.y; a.z += v.z; a.w += v.w;
}
#define FMA4G(acc, s, wp) { const float4 _w = *(const float4*)(wp); \
    acc.x += (s) * _w.x; acc.y += (s) * _w.y; acc.z += (s) * _w.z; acc.w += (s) * _w.w; }

__global__ __launch_bounds__(NT, 8) void gnn_fused(
    const float* __restrict__ x,
    const float* __restrict__ W1, const float* __restrict__ b1,
    const float* __restrict__ W2, const float* __restrict__ b2,
    const float* __restrict__ W3, const float* __restrict__ b3,
    float* __restrict__ out)
{
    __shared__ __align__(16) float smem[SMEMF];
    const int tid = threadIdx.x;
    const int lane = tid & 63, wid = tid >> 6;
    const int lr = lane & 15, lg = lane >> 4;
    const int bi = blockIdx.x / NBJ;
    const int bj = blockIdx.x % NBJ;
    const int oi = bi * TI, oj = bj * TJ;

    // ========== phase 0: g0 = dinv .* x (18x30); D3 plane; zero s1p pad rows ==========
    for (int n = tid; n < N0; n += NT) {
        int li = n / G0C, lj = n - li * G0C;
        int gi = oi - 3 + li, gj = oj - 3 + lj;
        float4 v = {0.f, 0.f, 0.f, 0.f};
        if ((unsigned)gi < HH && (unsigned)gj < HH) {
            float d = dinv_of(gi, gj);
            const float* xp = x + 3 * ((size_t)gi * HH + gj);
            v.x = d * xp[0]; v.y = d * xp[1]; v.z = d * xp[2];
        }
        *(float4*)&smem[G0O + n * 4] = v;
    }
    if (tid < NS1P) {     // dinv on L2 domain; 0 for out-of-grid AND pad rows 364..367
        float v = 0.f;
        if (tid < NS1) {
            int li = tid / R3C, lj = tid - li * R3C;
            int gi = oi - 1 + li, gj = oj - 1 + lj;
            if ((unsigned)gi < HH && (unsigned)gj < HH) v = dinv_of(gi, gj);
        }
        smem[D3O + tid] = v;
    }
    if (tid < 64)   // zero s1p pad rows 364..367 (tile 22's A-frag pad)
        smem[S1P + NS1 * 16 + tid] = 0.f;
    __syncthreads();

    // ============ phase 1: s0 + d2 into registers (one node/thread) ============
    float4 s0a = {0,0,0,0};
    float d2a = 0.f;
    if (tid < NS0) {
        int li = tid / S0C, lj = tid - li * S0C;
        int base = li * G0C + lj;
        #pragma unroll
        for (int di = 0; di < 3; ++di)
            #pragma unroll
            for (int dj = 0; dj < 3; ++dj)
                add4(s0a, *(const float4*)&smem[G0O + (base + di * G0C + dj) * 4]);
        int gi = oi - 2 + li, gj = oj - 2 + lj;
        if ((unsigned)gi < HH && (unsigned)gj < HH) d2a = dinv_of(gi, gj);
    }
    const int fli = tid / R3C, flj = tid - fli * R3C;
    const int fbase = fli * S0C + flj;
    __syncthreads();   // g0 dead; G1A/G1B may overlay

    // mm1 quad q from register s0 -> packed f16 (1 b64 write per node)
    #define MM1Q(q, BUF) \
        if (tid < NS0) { \
            float4 a = {0,0,0,0}; \
            FMA4G(a, s0a.x, W1 + 4 * (q)) FMA4G(a, s0a.y, W1 + 32 + 4 * (q)) FMA4G(a, s0a.z, W1 + 64 + 4 * (q)) \
            const float4 bb = *(const float4*)&b1[4 * (q)]; \
            float gx = d2a * fmaxf(d2a * a.x + bb.x, 0.f); \
            float gy = d2a * fmaxf(d2a * a.y + bb.y, 0.f); \
            float gz = d2a * fmaxf(d2a * a.z + bb.z, 0.f); \
            float gw = d2a * fmaxf(d2a * a.w + bb.w, 0.f); \
            uint2 u; u.x = BCU(PK(gx, gy)); u.y = BCU(PK(gz, gw)); \
            *(uint2*)&smem[(BUF) + tid * 2] = u; \
        }

    // bs2: 9-tap f16 boxsum of quad q -> s1p[row tid][u32 (2q,2q+1) ^ swz]
    #define BS2Q(q, BUF) \
        if (tid < NS1) { \
            const int _tb = (BUF) + fbase * 2; \
            const uint2 u00 = *(const uint2*)&smem[_tb + 0]; \
            const uint2 u01 = *(const uint2*)&smem[_tb + 2]; \
            const uint2 u02 = *(const uint2*)&smem[_tb + 4]; \
            const uint2 u10 = *(const uint2*)&smem[_tb + 2 * S0C + 0]; \
            const uint2 u11 = *(const uint2*)&smem[_tb + 2 * S0C + 2]; \
            const uint2 u12 = *(const uint2*)&smem[_tb + 2 * S0C + 4]; \
            const uint2 u20 = *(const uint2*)&smem[_tb + 4 * S0C + 0]; \
            const uint2 u21 = *(const uint2*)&smem[_tb + 4 * S0C + 2]; \
            const uint2 u22 = *(const uint2*)&smem[_tb + 4 * S0C + 4]; \
            h2 rl0 = (BC2(u00.x) + BC2(u01.x)) + BC2(u02.x); \
            h2 rl1 = (BC2(u10.x) + BC2(u11.x)) + BC2(u12.x); \
            h2 rl2 = (BC2(u20.x) + BC2(u21.x)) + BC2(u22.x); \
            h2 sl  = (rl0 + rl1) + rl2; \
            h2 rh0 = (BC2(u00.y) + BC2(u01.y)) + BC2(u02.y); \
            h2 rh1 = (BC2(u10.y) + BC2(u11.y)) + BC2(u12.y); \
            h2 rh2 = (BC2(u20.y) + BC2(u21.y)) + BC2(u22.y); \
            h2 sh  = (rh0 + rh1) + rh2; \
            uint2 uo; uo.x = BCU(sl); uo.y = BCU(sh); \
            *(uint2*)&smem[S1P + tid * 16 + (2 * (q) ^ SWZ(tid))] = uo; \
        }

    // ---- ping-pong over 8 channel-quads ----
    MM1Q(0, G1A) __syncthreads();
    BS2Q(0, G1A) MM1Q(1, G1B) __syncthreads();
    BS2Q(1, G1B) MM1Q(2, G1A) __syncthreads();
    BS2Q(2, G1A) MM1Q(3, G1B) __syncthreads();
    BS2Q(3, G1B) MM1Q(4, G1A) __syncthreads();
    BS2Q(4, G1A) MM1Q(5, G1B) __syncthreads();
    BS2Q(5, G1B) MM1Q(6, G1A) __syncthreads();
    BS2Q(6, G1A) MM1Q(7, G1B) __syncthreads();
    BS2Q(7, G1B)

    // per-lane MFMA B-fragments straight from global (L2-hot), hidden under BS2Q(7).
    uint4 uw20, uw21, uw3;
    {
        const int k0 = 8 * lg;
        uw20.x = BCU(PK(W2[(k0+0)*32 + lr],      W2[(k0+1)*32 + lr]));
        uw20.y = BCU(PK(W2[(k0+2)*32 + lr],      W2[(k0+3)*32 + lr]));
        uw20.z = BCU(PK(W2[(k0+4)*32 + lr],      W2[(k0+5)*32 + lr]));
        uw20.w = BCU(PK(W2[(k0+6)*32 + lr],      W2[(k0+7)*32 + lr]));
        uw21.x = BCU(PK(W2[(k0+0)*32 + 16 + lr], W2[(k0+1)*32 + 16 + lr]));
        uw21.y = BCU(PK(W2[(k0+2)*32 + 16 + lr], W2[(k0+3)*32 + 16 + lr]));
        uw21.z = BCU(PK(W2[(k0+4)*32 + 16 + lr], W2[(k0+5)*32 + 16 + lr]));
        uw21.w = BCU(PK(W2[(k0+6)*32 + 16 + lr], W2[(k0+7)*32 + 16 + lr]));
        float a0w=0.f,b0w=0.f,a1w=0.f,b1w=0.f,a2w=0.f,b2w=0.f,a3w=0.f,b3w=0.f;
        if (lr < 9) {
            a0w = W3[(k0+0)*9 + lr]; b0w = W3[(k0+1)*9 + lr];
            a1w = W3[(k0+2)*9 + lr]; b1w = W3[(k0+3)*9 + lr];
            a2w = W3[(k0+4)*9 + lr]; b2w = W3[(k0+5)*9 + lr];
            a3w = W3[(k0+6)*9 + lr]; b3w = W3[(k0+7)*9 + lr];
        }
        uw3.x = BCU(PK(a0w, b0w)); uw3.y = BCU(PK(a1w, b1w));
        uw3.z = BCU(PK(a2w, b2w)); uw3.w = BCU(PK(a3w, b3w));
    }
    const float b2c0 = b2[lr], b2c1 = b2[16 + lr];
    __syncthreads();   // s1p complete

    // ================= MFMA section (23 row-tiles, 3 per wave) =================
    const f16x8 bw20 = __builtin_bit_cast(f16x8, uw20);
    const f16x8 bw21 = __builtin_bit_cast(f16x8, uw21);
    const f16x8 bw3  = __builtin_bit_cast(f16x8, uw3);
    _Float16* hp = (_Float16*)smem;

    // mm2 + act + repack h (f16) IN-PLACE over s1p — wave-local tiles, no barrier.
    #define ACT1(dv, c0r, c1r, rr) { \
        const float dd_ = (dv); \
        float h0 = dd_ * fmaxf(dd_ * (c0r) + b2c0, 0.f); \
        float h1 = dd_ * fmaxf(dd_ * (c1r) + b2c1, 0.f); \
        const int row_ = nb + (rr); \
        const int sz_ = SWZ(row_); \
        hp[2 * (S1P + row_ * 16 + ((lr >> 1) ^ sz_)) + (lr & 1)] = (_Float16)h0; \
        hp[2 * (S1P + row_ * 16 + ((8 + (lr >> 1)) ^ sz_)) + (lr & 1)] = (_Float16)h1; }

    #define AFRAG(rt) __builtin_bit_cast(f16x8, \
        *(const uint4*)&smem[S1P + ((rt) * 16 + lr) * 16 + (4 * lg ^ SWZ((rt) * 16 + lr))])

    #define MM2TILE(rt) { \
        f16x8 aa = AFRAG(rt); \
        f32x4 c0 = {0.f, 0.f, 0.f, 0.f}, c1 = {0.f, 0.f, 0.f, 0.f}; \
        c0 = MFMA16(aa, bw20, c0); \
        c1 = MFMA16(aa, bw21, c1); \
        const int nb = (rt) * 16 + lg * 4; \
        const float4 dd = *(const float4*)&smem[D3O + nb]; \
        ACT1(dd.x, c0[0], c1[0], 0) \
        ACT1(dd.y, c0[1], c1[1], 1) \
        ACT1(dd.z, c0[2], c1[2], 2) \
        ACT1(dd.w, c0[3], c1[3], 3) }

    MM2TILE(wid)
    MM2TILE(wid + 8)
    if (wid < 7) { MM2TILE(wid + 16) }
    __syncthreads();   // all h writes done

    // load mm3 A-frags to registers BEFORE t overlays h rows
    f16x8 a30 = AFRAG(wid);
    f16x8 a31 = AFRAG(wid + 8);
    f16x8 a32 = a30;
    if (wid < 7) a32 = AFRAG(wid + 16);
    __syncthreads();   // every wave's A-frag loads complete before TB overlay

    #define MM3TILE(rt, af) { \
        f32x4 tt = {0.f, 0.f, 0.f, 0.f}; \
        tt = MFMA16((af), bw3, tt); \
        const int nb = (rt) * 16 + lg * 4; \
        if (lr < 4) { \
            smem[TB0 + (nb + 0) * 4 + lr] = tt[0]; \
            smem[TB0 + (nb + 1) * 4 + lr] = tt[1]; \
            smem[TB0 + (nb + 2) * 4 + lr] = tt[2]; \
            smem[TB0 + (nb + 3) * 4 + lr] = tt[3]; \
        } else if (lr < 8) { \
            smem[TB1 + (nb + 0) * 4 + lr - 4] = tt[0]; \
            smem[TB1 + (nb + 1) * 4 + lr - 4] = tt[1]; \
            smem[TB1 + (nb + 2) * 4 + lr - 4] = tt[2]; \
            smem[TB1 + (nb + 3) * 4 + lr - 4] = tt[3]; \
        } else if (lr == 8) { \
            smem[TB2 + nb + 0] = tt[0]; \
            smem[TB2 + nb + 1] = tt[1]; \
            smem[TB2 + nb + 2] = tt[2]; \
            smem[TB2 + nb + 3] = tt[3]; } }

    MM3TILE(wid, a30)
    MM3TILE(wid + 8, a31)
    if (wid < 7) { MM3TILE(wid + 16, a32) }
    __syncthreads();

    // ====== bs3 + epilogue: out = dinv*boxsum(t) + b3 -> planar outbuf ======
    for (int item = tid; item < 3 * ON; item += NT) {
        int p = item / ON, n = item - p * ON;
        int li = n / TJ, lj = n - li * TJ;
        int src = li * R3C + lj;
        float d = dinv_of(oi + li, oj + lj);
        if (p == 2) {
            float s = 0.f;
            #pragma unroll
            for (int di = 0; di < 3; ++di)
                #pragma unroll
                for (int dj = 0; dj < 3; ++dj)
                    s += smem[TB2 + src + di * R3C + dj];
            smem[OUT2 + n] = d * s + b3[8];
        } else {
            const int tb = p ? TB1 : TB0;
            float4 s = {0.f, 0.f, 0.f, 0.f};
            #pragma unroll
            for (int di = 0; di < 3; ++di)
                #pragma unroll
                for (int dj = 0; dj < 3; ++dj)
                    add4(s, *(const float4*)&smem[tb + (src + di * R3C + dj) * 4]);
            const float4 bb = *(const float4*)&b3[4 * p];
            float4 o;
            o.x = d * s.x + bb.x; o.y = d * s.y + bb.y;
            o.z = d * s.z + bb.z; o.w = d * s.w + bb.w;
            *(float4*)&smem[(p ? OUT1 : OUT0) + n * 4] = o;
        }
    }
    __syncthreads();

    // ====== pixel-shuffle write: 36 rows x 72 cols per block, float4 stores ======
    #define ORD(n, c) ((c) < 8 ? smem[((c) < 4 ? OUT0 : OUT1) + (n) * 4 + ((c) & 3)] \
                               : smem[OUT2 + (n)])
    for (int q = tid; q < 36 * 18; q += NT) {      // 648 float4 stores
        int rr = q / 18, cc0 = 4 * (q % 18);
        int ii = rr / 3, si = rr - 3 * ii;
        float4 o;
        { int cc = cc0 + 0, jj = cc / 3, sj = cc - 3 * jj; o.x = ORD(ii * TJ + jj, si * 3 + sj); }
        { int cc = cc0 + 1, jj = cc / 3, sj = cc - 3 * jj; o.y = ORD(ii * TJ + jj, si * 3 + sj); }
        { int cc = cc0 + 2, jj = cc / 3, sj = cc - 3 * jj; o.z = ORD(ii * TJ + jj, si * 3 + sj); }
        { int cc = cc0 + 3, jj = cc / 3, sj = cc - 3 * jj; o.w = ORD(ii * TJ + jj, si * 3 + sj); }
        *(float4*)&out[(size_t)(oi * SS + rr) * (HH * SS) + oj * SS + cc0] = o;
    }
}

extern "C" void kernel_launch(void* const* d_in, const int* in_sizes, int n_in,
                              void* d_out, int out_size, void* d_ws, size_t ws_size,
                              hipStream_t stream) {
    const float* x  = (const float*)d_in[0];
    // d_in[1] = edge_index (int32) — fixed grid; derived analytically.
    const float* W1 = (const float*)d_in[2];
    const float* b1 = (const float*)d_in[3];
    const float* W2 = (const float*)d_in[4];
    const float* b2 = (const float*)d_in[5];
    const float* W3 = (const float*)d_in[6];
    const float* b3 = (const float*)d_in[7];
    float* out = (float*)d_out;

    gnn_fused<<<dim3(64 * NBJ), dim3(NT), 0, stream>>>(x, W1, b1, W2, b2, W3, b3, out);
}

// Round 12
// 38.382 us; speedup vs baseline: 29.9982x; 1.0486x over previous
//
#include <hip/hip_runtime.h>

// SatelliteImageGNN: 3-layer GCN on a 768x768 8-neighbor grid + pixel shuffle.
// layer = dinv * boxsum3x3(dinv .* h) @ W + b ; dinv from position (edge_index unused).
// Round-12: s1 NEVER materialized. mm1 writes full 32-ch g1 [448][16 u32] in one
// phase; bs2 is fused into the MFMA A-fragment build (9 swizzled b128 taps +
// pk_add_f16 tree -> 2 MFMAs, per thread per row-tile). Barriers 15 -> 8.
// h repack in-place over g1. LDS 30.1 KB. Tile 12x24, grid 2048 = 2.0 rounds.

constexpr int HH = 768, SS = 3;
constexpr int TI = 12, TJ = 24;
constexpr int NBJ = 32;                 // 768/TJ
constexpr int NT = 512;

constexpr int G0C = 30;  constexpr int N0  = 540;   // g0: 18x30, origin (-3,-3)
constexpr int S0C = 28;  constexpr int NS0 = 448;   // s0/g1: 16x28, origin (-2,-2)
constexpr int R3C = 26;  constexpr int NS1 = 364;   // h/t: 14x26, origin (-1,-1)
constexpr int NS1P = 368;                           // 23 row-tiles of 16
constexpr int ON  = 288;                            // 12*24

// ---- LDS float offsets ----
constexpr int G1O = 0;                  // g1/h: 448 rows x 16 u32 (XOR-swizzled) = 7168
                                        // (g0 staging 0..2160 lives here ph0-ph1 only)
constexpr int D3O = 7168;               // 368 -> ..7536
constexpr int SMEMF = 7536;             // 30,144 B -> 4 blocks/CU

// overlays (barrier-protected):
constexpr int TB0 = 0;                  // t cols 0-3 : 368*4 = 1472
constexpr int TB1 = 1472;               // ..2944
constexpr int TB2 = 2944;               // ..3312
constexpr int OUT0 = 3328;              // [288][4] -> ..4480
constexpr int OUT1 = 4480;              // ..5632
constexpr int OUT2 = 5632;              // ..5920 (over dead g1/h rows)

// XOR swizzle on a 16-u32 row: quad-aligned, involutive
#define SWZ(row) ((((row) >> 1) & 3) << 2)

typedef _Float16 f16x8 __attribute__((ext_vector_type(8)));
typedef float    f32x4 __attribute__((ext_vector_type(4)));
using h2 = decltype(__builtin_amdgcn_cvt_pkrtz(0.f, 0.f));

#define PK(a, b)  __builtin_amdgcn_cvt_pkrtz((a), (b))
#define BC2(u)    __builtin_bit_cast(h2, (u))
#define BCU(x)    __builtin_bit_cast(uint32_t, (x))
#define MFMA16(a, b, c) __builtin_amdgcn_mfma_f32_16x16x32_f16((a), (b), (c), 0, 0, 0)

__device__ __forceinline__ float dinv_of(int gi, int gj) {
    int e = (1 + (gi > 0) + (gi < HH - 1)) * (1 + (gj > 0) + (gj < HH - 1));
    return e == 9 ? 0.33333334f : (e == 6 ? 0.40824829f : 0.5f);
}
__device__ __forceinline__ void add4(float4& a, const float4 v) {
    a.x += v.x; a.y += v.y; a.z += v.z; a.w += v.w;
}
#define FMA4G(acc, s, wp) { const float4 _w = *(const float4*)(wp); \
    acc.x += (s) * _w.x; acc.y += (s) * _w.y; acc.z += (s) * _w.z; acc.w += (s) * _w.w; }

__global__ __launch_bounds__(NT, 8) void gnn_fused(
    const float* __restrict__ x,
    const float* __restrict__ W1, const float* __restrict__ b1,
    const float* __restrict__ W2, const float* __restrict__ b2,
    const float* __restrict__ W3, const float* __restrict__ b3,
    float* __restrict__ out)
{
    __shared__ __align__(16) float smem[SMEMF];
    const int tid = threadIdx.x;
    const int lane = tid & 63, wid = tid >> 6;
    const int lr = lane & 15, lg = lane >> 4;
    const int bi = blockIdx.x / NBJ;
    const int bj = blockIdx.x % NBJ;
    const int oi = bi * TI, oj = bj * TJ;

    // ========== ph0: g0 = dinv .* x (18x30, over G1 region) + D3 plane ==========
    for (int n = tid; n < N0; n += NT) {
        int li = n / G0C, lj = n - li * G0C;
        int gi = oi - 3 + li, gj = oj - 3 + lj;
        float4 v = {0.f, 0.f, 0.f, 0.f};
        if ((unsigned)gi < HH && (unsigned)gj < HH) {
            float d = dinv_of(gi, gj);
            const float* xp = x + 3 * ((size_t)gi * HH + gj);
            v.x = d * xp[0]; v.y = d * xp[1]; v.z = d * xp[2];
        }
        *(float4*)&smem[G1O + n * 4] = v;
    }
    if (tid < NS1P) {     // dinv on L2 domain; 0 for out-of-grid AND pad rows 364..367
        float v = 0.f;
        if (tid < NS1) {
            int li = tid / R3C, lj = tid - li * R3C;
            int gi = oi - 1 + li, gj = oj - 1 + lj;
            if ((unsigned)gi < HH && (unsigned)gj < HH) v = dinv_of(gi, gj);
        }
        smem[D3O + tid] = v;
    }
    __syncthreads();

    // ========== ph1: bs1 -> registers (one s0 node/thread) ==========
    float4 s0a = {0,0,0,0};
    float d2a = 0.f;
    if (tid < NS0) {
        int li = tid / S0C, lj = tid - li * S0C;
        int base = li * G0C + lj;
        #pragma unroll
        for (int di = 0; di < 3; ++di)
            #pragma unroll
            for (int dj = 0; dj < 3; ++dj)
                add4(s0a, *(const float4*)&smem[G1O + (base + di * G0C + dj) * 4]);
        int gi = oi - 2 + li, gj = oj - 2 + lj;
        if ((unsigned)gi < HH && (unsigned)gj < HH) d2a = dinv_of(gi, gj);
    }
    // per-thread A-row bases for the fused bs2 (L2-domain node -> S0-domain offset)
    const int nA0 = wid * 16 + lr;
    const int nA1 = (wid + 8) * 16 + lr;
    const int nA2 = (wid + 16) * 16 + lr;     // only used when wid < 7 (n <= 367)
    const int fb0 = (nA0 / R3C) * S0C + (nA0 % R3C);
    const int fb1 = (nA1 / R3C) * S0C + (nA1 % R3C);
    const int fb2 = (nA2 / R3C) * S0C + (nA2 % R3C);
    __syncthreads();   // g0 dead; g1 may overwrite

    // per-lane MFMA B-fragments straight from global (L2-hot), scheduled early.
    uint4 uw20, uw21, uw3;
    {
        const int k0 = 8 * lg;
        uw20.x = BCU(PK(W2[(k0+0)*32 + lr],      W2[(k0+1)*32 + lr]));
        uw20.y = BCU(PK(W2[(k0+2)*32 + lr],      W2[(k0+3)*32 + lr]));
        uw20.z = BCU(PK(W2[(k0+4)*32 + lr],      W2[(k0+5)*32 + lr]));
        uw20.w = BCU(PK(W2[(k0+6)*32 + lr],      W2[(k0+7)*32 + lr]));
        uw21.x = BCU(PK(W2[(k0+0)*32 + 16 + lr], W2[(k0+1)*32 + 16 + lr]));
        uw21.y = BCU(PK(W2[(k0+2)*32 + 16 + lr], W2[(k0+3)*32 + 16 + lr]));
        uw21.z = BCU(PK(W2[(k0+4)*32 + 16 + lr], W2[(k0+5)*32 + 16 + lr]));
        uw21.w = BCU(PK(W2[(k0+6)*32 + 16 + lr], W2[(k0+7)*32 + 16 + lr]));
        float a0w=0.f,b0w=0.f,a1w=0.f,b1w=0.f,a2w=0.f,b2w=0.f,a3w=0.f,b3w=0.f;
        if (lr < 9) {
            a0w = W3[(k0+0)*9 + lr]; b0w = W3[(k0+1)*9 + lr];
            a1w = W3[(k0+2)*9 + lr]; b1w = W3[(k0+3)*9 + lr];
            a2w = W3[(k0+4)*9 + lr]; b2w = W3[(k0+5)*9 + lr];
            a3w = W3[(k0+6)*9 + lr]; b3w = W3[(k0+7)*9 + lr];
        }
        uw3.x = BCU(PK(a0w, b0w)); uw3.y = BCU(PK(a1w, b1w));
        uw3.z = BCU(PK(a2w, b2w)); uw3.w = BCU(PK(a3w, b3w));
    }
    const float b2c0 = b2[lr], b2c1 = b2[16 + lr];

    // ========== ph2: mm1 ALL 32 channels -> g1[448][16 u32] (swizzled) ==========
    if (tid < NS0) {
        uint32_t g[16];
        #pragma unroll
        for (int q = 0; q < 8; ++q) {
            float4 a = {0,0,0,0};
            FMA4G(a, s0a.x, W1 + 4 * q)
            FMA4G(a, s0a.y, W1 + 32 + 4 * q)
            FMA4G(a, s0a.z, W1 + 64 + 4 * q)
            const float4 bb = *(const float4*)&b1[4 * q];
            float gx = d2a * fmaxf(d2a * a.x + bb.x, 0.f);
            float gy = d2a * fmaxf(d2a * a.y + bb.y, 0.f);
            float gz = d2a * fmaxf(d2a * a.z + bb.z, 0.f);
            float gw = d2a * fmaxf(d2a * a.w + bb.w, 0.f);
            g[2 * q]     = BCU(PK(gx, gy));
            g[2 * q + 1] = BCU(PK(gz, gw));
        }
        const int sz = SWZ(tid);
        uint4 u;
        u.x = g[0];  u.y = g[1];  u.z = g[2];  u.w = g[3];
        *(uint4*)&smem[G1O + tid * 16 + (0 ^ sz)] = u;
        u.x = g[4];  u.y = g[5];  u.z = g[6];  u.w = g[7];
        *(uint4*)&smem[G1O + tid * 16 + (4 ^ sz)] = u;
        u.x = g[8];  u.y = g[9];  u.z = g[10]; u.w = g[11];
        *(uint4*)&smem[G1O + tid * 16 + (8 ^ sz)] = u;
        u.x = g[12]; u.y = g[13]; u.z = g[14]; u.w = g[15];
        *(uint4*)&smem[G1O + tid * 16 + (12 ^ sz)] = u;
    }
    __syncthreads();

    // ========== ph3: fused bs2 (in-register) + mm2 MFMAs ==========
    const f16x8 bw20 = __builtin_bit_cast(f16x8, uw20);
    const f16x8 bw21 = __builtin_bit_cast(f16x8, uw21);
    const f16x8 bw3  = __builtin_bit_cast(f16x8, uw3);

    #define TAP(rr) (*(const uint4*)&smem[G1O + (rr) * 16 + ((4 * lg) ^ SWZ(rr))])
    #define ROWSUM(rr, o0, o1, o2) { \
        const uint4 va = TAP((rr)+(o0)); const uint4 vb = TAP((rr)+(o1)); const uint4 vc = TAP((rr)+(o2)); \
        r0 = (BC2(va.x) + BC2(vb.x)) + BC2(vc.x); \
        r1 = (BC2(va.y) + BC2(vb.y)) + BC2(vc.y); \
        r2 = (BC2(va.z) + BC2(vb.z)) + BC2(vc.z); \
        r3 = (BC2(va.w) + BC2(vb.w)) + BC2(vc.w); }

    #define BS2MM2(fb, cc0, cc1) { \
        h2 r0, r1, r2, r3, s0_, s1_, s2_, s3_; \
        ROWSUM((fb), 0, 1, 2)               s0_ = r0; s1_ = r1; s2_ = r2; s3_ = r3; \
        ROWSUM((fb) + S0C, 0, 1, 2)         s0_ += r0; s1_ += r1; s2_ += r2; s3_ += r3; \
        ROWSUM((fb) + 2 * S0C, 0, 1, 2)     s0_ += r0; s1_ += r1; s2_ += r2; s3_ += r3; \
        uint4 af_; af_.x = BCU(s0_); af_.y = BCU(s1_); af_.z = BCU(s2_); af_.w = BCU(s3_); \
        const f16x8 aa_ = __builtin_bit_cast(f16x8, af_); \
        cc0 = MFMA16(aa_, bw20, cc0); \
        cc1 = MFMA16(aa_, bw21, cc1); }

    f32x4 c00 = {0,0,0,0}, c01 = {0,0,0,0};
    f32x4 c10 = {0,0,0,0}, c11 = {0,0,0,0};
    f32x4 c20 = {0,0,0,0}, c21 = {0,0,0,0};
    BS2MM2(fb0, c00, c01)
    BS2MM2(fb1, c10, c11)
    if (wid < 7) { BS2MM2(fb2, c20, c21) }
    __syncthreads();   // all g1 reads done

    // ========== ph4: act + write h (f16) over g1 region (swizzled rows) ==========
    _Float16* hp = (_Float16*)smem;
    #define WRH(rt, cc0, cc1) { \
        const int nb = (rt) * 16 + lg * 4; \
        const float4 dd = *(const float4*)&smem[D3O + nb]; \
        _Pragma("unroll") \
        for (int r = 0; r < 4; ++r) { \
            const float dv = r == 0 ? dd.x : (r == 1 ? dd.y : (r == 2 ? dd.z : dd.w)); \
            const float h0 = dv * fmaxf(dv * cc0[r] + b2c0, 0.f); \
            const float h1 = dv * fmaxf(dv * cc1[r] + b2c1, 0.f); \
            const int row_ = nb + r; \
            const int sz_ = SWZ(row_); \
            hp[2 * (G1O + row_ * 16 + (((lr >> 1)) ^ sz_)) + (lr & 1)] = (_Float16)h0; \
            hp[2 * (G1O + row_ * 16 + ((8 + (lr >> 1)) ^ sz_)) + (lr & 1)] = (_Float16)h1; } }

    WRH(wid, c00, c01)
    WRH(wid + 8, c10, c11)
    if (wid < 7) { WRH(wid + 16, c20, c21) }
    __syncthreads();   // h complete

    // ========== ph5a: load mm3 A-frags BEFORE t overlays h rows ==========
    #define AFRAG(rt) __builtin_bit_cast(f16x8, \
        *(const uint4*)&smem[G1O + ((rt) * 16 + lr) * 16 + ((4 * lg) ^ SWZ((rt) * 16 + lr))])
    f16x8 a30 = AFRAG(wid);
    f16x8 a31 = AFRAG(wid + 8);
    f16x8 a32 = a30;
    if (wid < 7) a32 = AFRAG(wid + 16);
    __syncthreads();

    // ========== ph5b: mm3 + scatter t to TB planes ==========
    #define MM3TILE(rt, af) { \
        f32x4 tt = {0.f, 0.f, 0.f, 0.f}; \
        tt = MFMA16((af), bw3, tt); \
        const int nb = (rt) * 16 + lg * 4; \
        if (lr < 4) { \
            smem[TB0 + (nb + 0) * 4 + lr] = tt[0]; \
            smem[TB0 + (nb + 1) * 4 + lr] = tt[1]; \
            smem[TB0 + (nb + 2) * 4 + lr] = tt[2]; \
            smem[TB0 + (nb + 3) * 4 + lr] = tt[3]; \
        } else if (lr < 8) { \
            smem[TB1 + (nb + 0) * 4 + lr - 4] = tt[0]; \
            smem[TB1 + (nb + 1) * 4 + lr - 4] = tt[1]; \
            smem[TB1 + (nb + 2) * 4 + lr - 4] = tt[2]; \
            smem[TB1 + (nb + 3) * 4 + lr - 4] = tt[3]; \
        } else if (lr == 8) { \
            smem[TB2 + nb + 0] = tt[0]; \
            smem[TB2 + nb + 1] = tt[1]; \
            smem[TB2 + nb + 2] = tt[2]; \
            smem[TB2 + nb + 3] = tt[3]; } }

    MM3TILE(wid, a30)
    MM3TILE(wid + 8, a31)
    if (wid < 7) { MM3TILE(wid + 16, a32) }
    __syncthreads();

    // ====== bs3 + epilogue: out = dinv*boxsum(t) + b3 -> planar outbuf ======
    for (int item = tid; item < 3 * ON; item += NT) {
        int p = item / ON, n = item - p * ON;
        int li = n / TJ, lj = n - li * TJ;
        int src = li * R3C + lj;
        float d = dinv_of(oi + li, oj + lj);
        if (p == 2) {
            float s = 0.f;
            #pragma unroll
            for (int di = 0; di < 3; ++di)
                #pragma unroll
                for (int dj = 0; dj < 3; ++dj)
                    s += smem[TB2 + src + di * R3C + dj];
            smem[OUT2 + n] = d * s + b3[8];
        } else {
            const int tb = p ? TB1 : TB0;
            float4 s = {0.f, 0.f, 0.f, 0.f};
            #pragma unroll
            for (int di = 0; di < 3; ++di)
                #pragma unroll
                for (int dj = 0; dj < 3; ++dj)
                    add4(s, *(const float4*)&smem[tb + (src + di * R3C + dj) * 4]);
            const float4 bb = *(const float4*)&b3[4 * p];
            float4 o;
            o.x = d * s.x + bb.x; o.y = d * s.y + bb.y;
            o.z = d * s.z + bb.z; o.w = d * s.w + bb.w;
            *(float4*)&smem[(p ? OUT1 : OUT0) + n * 4] = o;
        }
    }
    __syncthreads();

    // ====== pixel-shuffle write: 36 rows x 72 cols per block, float4 stores ======
    #define ORD(n, c) ((c) < 8 ? smem[((c) < 4 ? OUT0 : OUT1) + (n) * 4 + ((c) & 3)] \
                               : smem[OUT2 + (n)])
    for (int q = tid; q < 36 * 18; q += NT) {      // 648 float4 stores
        int rr = q / 18, cc0 = 4 * (q % 18);
        int ii = rr / 3, si = rr - 3 * ii;
        float4 o;
        { int cc = cc0 + 0, jj = cc / 3, sj = cc - 3 * jj; o.x = ORD(ii * TJ + jj, si * 3 + sj); }
        { int cc = cc0 + 1, jj = cc / 3, sj = cc - 3 * jj; o.y = ORD(ii * TJ + jj, si * 3 + sj); }
        { int cc = cc0 + 2, jj = cc / 3, sj = cc - 3 * jj; o.z = ORD(ii * TJ + jj, si * 3 + sj); }
        { int cc = cc0 + 3, jj = cc / 3, sj = cc - 3 * jj; o.w = ORD(ii * TJ + jj, si * 3 + sj); }
        *(float4*)&out[(size_t)(oi * SS + rr) * (HH * SS) + oj * SS + cc0] = o;
    }
}

extern "C" void kernel_launch(void* const* d_in, const int* in_sizes, int n_in,
                              void* d_out, int out_size, void* d_ws, size_t ws_size,
                              hipStream_t stream) {
    const float* x  = (const float*)d_in[0];
    // d_in[1] = edge_index (int32) — fixed grid; derived analytically.
    const float* W1 = (const float*)d_in[2];
    const float* b1 = (const float*)d_in[3];
    const float* W2 = (const float*)d_in[4];
    const float* b2 = (const float*)d_in[5];
    const float* W3 = (const float*)d_in[6];
    const float* b3 = (const float*)d_in[7];
    float* out = (float*)d_out;

    gnn_fused<<<dim3(64 * NBJ), dim3(NT), 0, stream>>>(x, W1, b1, W2, b2, W3, b3, out);
}